// Round 1
// baseline (724.069 us; speedup 1.0000x reference)
//
#include <hip/hip_runtime.h>

// ConvertParamsTEtoParams0TEGaussLayer: B=65536 independent 16x16 f32 problems.
// One block (256 threads) per batch; thread t=(i*16+j) owns element (i,j).
// All intermediates in LDS. Unpivoted Gauss-Jordan for inv(prec_h) (SPD,
// well-conditioned), level-scheduled forward substitution for inv(chol_amat)
// (unit lower triangular).

constexpr int N = 16;

#define ROW(M, r, c) M[(r) * 16 + (c)]

__global__ __launch_bounds__(256) void gauss_te_kernel(
    const float* __restrict__ mu_TE,      // (B, 32)
    const float* __restrict__ prec_h,     // (B,16,16)
    const float* __restrict__ chol_v,
    const float* __restrict__ chol_h,
    const float* __restrict__ chol_hv,
    const float* __restrict__ chol_v_TE,
    const float* __restrict__ chol_h_TE,
    const float* __restrict__ chol_hv_TE,
    const float* __restrict__ chol_amat,
    float* __restrict__ out,              // [B*256] cholv_TE_std, then [B*16] muv_TE
    int B)
{
  const int b = blockIdx.x;
  const int t = threadIdx.x;          // 0..255
  const int i = t >> 4;
  const int j = t & 15;
  const size_t off = (size_t)b * 256;

  __shared__ float Pinv[256], Lh[256], Hv[256], LhT[256], HvT[256],
      La[256], Lv[256], LvT[256], sym[256], tmp[256], PiTE[256],
      M1[256], M2[256], M3[256], amatTE[256], cinv[256], t2[256], camTE[256];

  // ---- stage inputs (fully coalesced, 1 float/thread/array) ----
  Pinv[t] = prec_h[off + t];
  Lh[t]   = chol_h[off + t];
  Hv[t]   = chol_hv[off + t];
  LhT[t]  = chol_h_TE[off + t];
  HvT[t]  = chol_hv_TE[off + t];
  La[t]   = chol_amat[off + t];
  Lv[t]   = chol_v[off + t];
  LvT[t]  = chol_v_TE[off + t];
  // muv_TE = mu_TE[:, :16]
  if (t < N) out[(size_t)B * 256 + (size_t)b * N + t] = mu_TE[(size_t)b * 32 + t];
  __syncthreads();

  // ---- Pinv = inv(prec_h): in-place Gauss-Jordan, no pivoting (SPD) ----
  #pragma unroll 1
  for (int k = 0; k < N; ++k) {
    const float piv = ROW(Pinv, k, k);
    const float aik = ROW(Pinv, i, k);
    const float akj = ROW(Pinv, k, j);
    const float aij = Pinv[t];
    __syncthreads();                 // all reads done before any write
    const float pivinv = 1.0f / piv;
    float nv;
    if (i == k)       nv = (j == k) ? pivinv : akj * pivinv;
    else if (j == k)  nv = -aik * pivinv;
    else              nv = aij - aik * akj * pivinv;
    Pinv[t] = nv;
    __syncthreads();                 // writes visible for next step
  }

  // ---- sym = LhT@Lh^T + Lh@LhT^T + HvT@Hv^T + Hv@HvT^T ----
  {
    float s = 0.f;
    #pragma unroll
    for (int k = 0; k < N; ++k)
      s += ROW(LhT, i, k) * ROW(Lh, j, k) + ROW(Lh, i, k) * ROW(LhT, j, k)
         + ROW(HvT, i, k) * ROW(Hv, j, k) + ROW(Hv, i, k) * ROW(HvT, j, k);
    sym[t] = s;
  }
  __syncthreads();

  // ---- PiTE = -(Pinv @ sym @ Pinv) ----
  {
    float s = 0.f;
    #pragma unroll
    for (int k = 0; k < N; ++k) s += ROW(Pinv, i, k) * ROW(sym, k, j);
    tmp[t] = s;
  }
  __syncthreads();
  {
    float s = 0.f;
    #pragma unroll
    for (int k = 0; k < N; ++k) s += ROW(tmp, i, k) * ROW(Pinv, k, j);
    PiTE[t] = -s;
  }
  __syncthreads();

  // ---- M1 = Pinv@Hv, M2 = PiTE@Hv, M3 = Pinv@HvT ----
  {
    float s1 = 0.f, s2 = 0.f, s3 = 0.f;
    #pragma unroll
    for (int k = 0; k < N; ++k) {
      s1 += ROW(Pinv, i, k) * ROW(Hv, k, j);
      s2 += ROW(PiTE, i, k) * ROW(Hv, k, j);
      s3 += ROW(Pinv, i, k) * ROW(HvT, k, j);
    }
    M1[t] = s1; M2[t] = s2; M3[t] = s3;
  }
  __syncthreads();

  // ---- amatTE = -(HvT^T@M1 + Hv^T@M2 + Hv^T@M3) ----
  {
    float s = 0.f;
    #pragma unroll
    for (int k = 0; k < N; ++k)
      s += ROW(HvT, k, i) * ROW(M1, k, j)
         + ROW(Hv, k, i) * (ROW(M2, k, j) + ROW(M3, k, j));
    amatTE[t] = -s;
  }
  __syncthreads();

  // ---- cinv = inv(chol_amat), unit lower triangular, level scheduling ----
  cinv[t] = (i == j) ? 1.0f : 0.0f;
  __syncthreads();
  #pragma unroll 1
  for (int s = 1; s < N; ++s) {
    float v = 0.f;
    const bool act = (i - j == s);
    if (act) {
      for (int k = j; k < i; ++k) v += ROW(La, i, k) * ROW(cinv, k, j);
      v = -v;
    }
    __syncthreads();
    if (act) cinv[t] = v;
    __syncthreads();
  }

  // ---- arg = cinv @ amatTE @ cinv^T; masked = arg * phi ----
  {
    float s = 0.f;
    #pragma unroll
    for (int k = 0; k < N; ++k) s += ROW(cinv, i, k) * ROW(amatTE, k, j);
    t2[t] = s;
  }
  __syncthreads();
  {
    float s = 0.f;
    #pragma unroll
    for (int k = 0; k < N; ++k) s += ROW(t2, i, k) * ROW(cinv, j, k);
    // phi_mask: strict lower = 1, diag = 0.5, upper = 0
    tmp[t] = (i > j) ? s : ((i == j) ? 0.5f * s : 0.0f);
  }
  __syncthreads();

  // ---- camTE = La @ masked ----
  {
    float s = 0.f;
    #pragma unroll
    for (int k = 0; k < N; ++k) s += ROW(La, i, k) * ROW(tmp, k, j);
    camTE[t] = s;
  }
  __syncthreads();

  // ---- out = LvT@La + Lv@camTE ----
  {
    float s = 0.f;
    #pragma unroll
    for (int k = 0; k < N; ++k)
      s += ROW(LvT, i, k) * ROW(La, k, j) + ROW(Lv, i, k) * ROW(camTE, k, j);
    out[off + t] = s;
  }
}

extern "C" void kernel_launch(void* const* d_in, const int* in_sizes, int n_in,
                              void* d_out, int out_size, void* d_ws, size_t ws_size,
                              hipStream_t stream) {
  const float* mu_TE      = (const float*)d_in[0];
  const float* prec_h     = (const float*)d_in[1];
  const float* chol_v     = (const float*)d_in[2];
  const float* chol_h     = (const float*)d_in[3];
  const float* chol_hv    = (const float*)d_in[4];
  const float* chol_v_TE  = (const float*)d_in[5];
  const float* chol_h_TE  = (const float*)d_in[6];
  const float* chol_hv_TE = (const float*)d_in[7];
  const float* chol_amat  = (const float*)d_in[8];
  float* out = (float*)d_out;

  const int B = in_sizes[0] / 32;   // mu_TE is (B, NV+NH=32)
  gauss_te_kernel<<<B, 256, 0, stream>>>(mu_TE, prec_h, chol_v, chol_h, chol_hv,
                                         chol_v_TE, chol_h_TE, chol_hv_TE,
                                         chol_amat, out, B);
}

// Round 2
// 424.998 us; speedup vs baseline: 1.7037x; 1.7037x over previous
//
#include <hip/hip_runtime.h>

// ConvertParamsTEtoParams0TEGaussLayer — wave-cooperative systolic version.
// 64-thread blocks = 1 wave = 4 independent batches (16 lanes per batch).
// Lane i holds row i of each 16x16 matrix in registers. Matmuls are 16-step
// systolic passes: B-rows rotate through lanes via DPP row_ror:1 (VALU pipe);
// the A scalar is a single conflict-free ds_read_b32 per step from a
// row-major LDS copy. Only 3 LDS matrix slots per batch are ever live.
//
// Algebra: Pinv symmetric => prec_h_inv_TE = -(W + W^T), W = Pinv@S@Pinv,
// S = chol_h_TE@chol_h^T + chol_hv_TE@chol_hv^T  (sym = S + S^T).
// cinv of unit-lower chol_amat via per-lane-column forward substitution.

constexpr int ROWF = 20;          // LDS row pitch in floats (16 + 4 pad, 16B-aligned)
constexpr int BSTR = 328;         // per-batch stride within a slot (floats, bank-skewed)
constexpr int SLOTF = 4 * BSTR;   // slot stride (4 batches per wave)

__device__ __forceinline__ float rot_up1(float x) {
  // DPP ROW_ROR:1 : dst[lane] = src[(lane-1) & 15] within each 16-lane row.
  // After s applications, lane i holds the value lane (i-s)&15 started with.
  return __int_as_float(__builtin_amdgcn_update_dpp(
      0, __float_as_int(x), 0x121, 0xF, 0xF, false));
}

__device__ __forceinline__ void load_rows_g(const float* __restrict__ gsrc,
                                            size_t batch, int i, float (&v)[16]) {
  const float4* s = reinterpret_cast<const float4*>(gsrc + batch * 256 + (size_t)i * 16);
  #pragma unroll
  for (int c = 0; c < 4; ++c) {
    float4 q = s[c];
    v[4*c+0] = q.x; v[4*c+1] = q.y; v[4*c+2] = q.z; v[4*c+3] = q.w;
  }
}

__device__ __forceinline__ void store_rows_l(float* dst, int i, const float (&v)[16]) {
  #pragma unroll
  for (int c = 0; c < 4; ++c)
    reinterpret_cast<float4*>(dst + i * ROWF)[c] =
        make_float4(v[4*c], v[4*c+1], v[4*c+2], v[4*c+3]);
}

__device__ __forceinline__ void load_cols_l(const float* src, int i, float (&v)[16]) {
  #pragma unroll
  for (int c = 0; c < 16; ++c) v[c] = src[c * ROWF + i];   // row i of src^T
}

// C += A @ B      (TR=false): av = A[i][k]
// C += A^T @ B    (TR=true) : av = A[k][i]
// A in LDS (row-major, pitch ROWF); B as register rows (lane i = row i),
// rotated in place and restored after 16 steps; C accumulates in registers.
template<bool TR>
__device__ __forceinline__ void mm_pass(const float* __restrict__ A, int i,
                                        float (&b)[16], float (&c)[16]) {
  float av = A[i * ROWF + i];                 // k0 = i: same element both modes
  #pragma unroll 1
  for (int s = 0; s < 16; ++s) {
    const int kn = (i - s - 1) & 15;          // prefetch next step's scalar
    const float avn = TR ? A[kn * ROWF + i] : A[i * ROWF + kn];
    #pragma unroll
    for (int j = 0; j < 16; ++j) c[j] = fmaf(av, b[j], c[j]);
    #pragma unroll
    for (int j = 0; j < 16; ++j) b[j] = rot_up1(b[j]);
    av = avn;
  }
}

__global__ __launch_bounds__(64) void gauss_te_wave(
    const float* __restrict__ mu_TE,      // (B, 32)
    const float* __restrict__ prec_h,
    const float* __restrict__ chol_v,
    const float* __restrict__ chol_h,
    const float* __restrict__ chol_hv,
    const float* __restrict__ chol_v_TE,
    const float* __restrict__ chol_h_TE,
    const float* __restrict__ chol_hv_TE,
    const float* __restrict__ chol_amat,
    float* __restrict__ out, int B)
{
  __shared__ float slab[3 * SLOTF];
  const int t = threadIdx.x;
  const int g = t >> 4;                 // batch group within wave (0..3)
  const int i = t & 15;                 // row owned by this lane
  const size_t batch = (size_t)blockIdx.x * 4 + g;

  float* S0 = slab + 0 * SLOTF + g * BSTR;
  float* S1 = slab + 1 * SLOTF + g * BSTR;
  float* S2 = slab + 2 * SLOTF + g * BSTR;

  // ---- muv_TE passthrough ----
  out[(size_t)B * 256 + batch * 16 + i] = mu_TE[batch * 32 + i];

  // ---- Pinv = inv(prec_h): in-place GJ, rows in regs, pivot row via LDS ----
  float p[16];
  load_rows_g(prec_h, batch, i, p);
  #pragma unroll
  for (int k = 0; k < 16; ++k) {
    float* buf = S0 + (k & 1) * 16;     // double-buffered broadcast row
    if (i == k) {
      const float piv = 1.0f / p[k];
      float tt[16];
      #pragma unroll
      for (int c = 0; c < 16; ++c) tt[c] = p[c] * piv;
      tt[k] = piv;
      #pragma unroll
      for (int c = 0; c < 4; ++c)
        reinterpret_cast<float4*>(buf)[c] =
            make_float4(tt[4*c], tt[4*c+1], tt[4*c+2], tt[4*c+3]);
    }
    __syncthreads();                    // 1-wave block: cheap ordering fence
    float br[16];
    #pragma unroll
    for (int c = 0; c < 4; ++c) {
      float4 q = reinterpret_cast<const float4*>(buf)[c];
      br[4*c+0] = q.x; br[4*c+1] = q.y; br[4*c+2] = q.z; br[4*c+3] = q.w;
    }
    if (i != k) {
      const float f = p[k];
      #pragma unroll
      for (int c = 0; c < 16; ++c) p[c] = fmaf(-f, br[c], p[c]);
      p[k] = -f * br[k];
    } else {
      #pragma unroll
      for (int c = 0; c < 16; ++c) p[c] = br[c];
    }
    __syncthreads();
  }
  store_rows_l(S0, i, p);               // Pinv -> S0 (A-role copy)
  __syncthreads();

  // ---- S = LhT@Lh^T + HvT@Hv^T ----
  float sacc[16];
  #pragma unroll
  for (int j = 0; j < 16; ++j) sacc[j] = 0.f;

  float tmp16[16], bb[16];
  load_rows_g(chol_h, batch, i, tmp16);       // Lh
  store_rows_l(S1, i, tmp16);
  load_rows_g(chol_h_TE, batch, i, tmp16);    // LhT
  store_rows_l(S2, i, tmp16);
  __syncthreads();
  load_cols_l(S1, i, bb);                     // rows of Lh^T
  mm_pass<false>(S2, i, bb, sacc);            // += LhT @ Lh^T

  float hv[16], hvT[16];
  load_rows_g(chol_hv, batch, i, hv);
  store_rows_l(S1, i, hv);
  load_rows_g(chol_hv_TE, batch, i, hvT);
  store_rows_l(S2, i, hvT);
  __syncthreads();
  load_cols_l(S1, i, bb);                     // rows of Hv^T
  mm_pass<false>(S2, i, bb, sacc);            // += HvT @ Hv^T

  // ---- W = (Pinv@S)@Pinv ; PiTE = -(W + W^T) ----
  float w1[16];
  #pragma unroll
  for (int j = 0; j < 16; ++j) w1[j] = 0.f;
  mm_pass<false>(S0, i, sacc, w1);            // W1 = Pinv@S
  store_rows_l(S1, i, w1);
  __syncthreads();
  float w[16];
  #pragma unroll
  for (int j = 0; j < 16; ++j) w[j] = 0.f;
  mm_pass<false>(S1, i, p, w);                // W = W1@Pinv (B = Pinv regs)
  store_rows_l(S1, i, w);
  __syncthreads();
  float pite[16];
  {
    float wc[16];
    load_cols_l(S1, i, wc);                   // row i of W^T
    #pragma unroll
    for (int j = 0; j < 16; ++j) pite[j] = -(w[j] + wc[j]);
  }

  // ---- M1 = Pinv@Hv ; M23 = Pinv@HvT + PiTE@Hv ----
  float m1[16], m23[16];
  #pragma unroll
  for (int j = 0; j < 16; ++j) { m1[j] = 0.f; m23[j] = 0.f; }
  mm_pass<false>(S0, i, hv, m1);              // M1 = Pinv@Hv
  mm_pass<false>(S0, i, hvT, m23);            // M3 = Pinv@HvT
  store_rows_l(S0, i, pite);                  // PiTE -> S0 (Pinv LDS dead)
  __syncthreads();
  mm_pass<false>(S0, i, hv, m23);             // += M2 = PiTE@Hv

  // ---- amatTE = -(HvT^T@M1 + Hv^T@M23) ----
  store_rows_l(S1, i, hv);                    // Hv -> S1 (S2 still holds HvT)
  __syncthreads();
  float am[16];
  #pragma unroll
  for (int j = 0; j < 16; ++j) am[j] = 0.f;
  mm_pass<true>(S2, i, m1, am);               // HvT^T @ M1
  mm_pass<true>(S1, i, m23, am);              // Hv^T  @ M23
  #pragma unroll
  for (int j = 0; j < 16; ++j) am[j] = -am[j];

  // ---- cinv: forward substitution, lane i = column i (diag = 1) ----
  float la[16];
  load_rows_g(chol_amat, batch, i, la);
  store_rows_l(S0, i, la);                    // La -> S0
  __syncthreads();
  float x[16];                                // x[r] = cinv[r][i]
  #pragma unroll
  for (int r = 0; r < 16; ++r) {
    float s = (i == r) ? 1.0f : 0.0f;
    #pragma unroll
    for (int k = 0; k < 16; ++k)
      if (k < r) s = fmaf(-S0[r * ROWF + k], x[k], s);
    x[r] = s;
  }

  // ---- Y = amatTE@cinv^T ; arg = cinv@Y ; masked = arg*phi ----
  store_rows_l(S1, i, am);                    // amatTE -> S1
  store_rows_l(S2, i, x);                     // cinv^T -> S2 (row i = col i of cinv)
  __syncthreads();
  float y[16];
  #pragma unroll
  for (int j = 0; j < 16; ++j) y[j] = 0.f;
  mm_pass<false>(S1, i, x, y);                // B rows = cinv^T rows = x
  float arg[16];
  #pragma unroll
  for (int j = 0; j < 16; ++j) arg[j] = 0.f;
  mm_pass<true>(S2, i, y, arg);               // cinvT^T = cinv as A
  #pragma unroll
  for (int j = 0; j < 16; ++j)
    arg[j] = (j < i) ? arg[j] : ((j == i) ? 0.5f * arg[j] : 0.0f);

  // ---- camTE = La @ masked ----
  float cam[16];
  #pragma unroll
  for (int j = 0; j < 16; ++j) cam[j] = 0.f;
  mm_pass<false>(S0, i, arg, cam);

  // ---- out = LvT@La + Lv@camTE ----
  load_rows_g(chol_v_TE, batch, i, tmp16);    // LvT
  store_rows_l(S1, i, tmp16);
  load_rows_g(chol_v, batch, i, tmp16);       // Lv
  store_rows_l(S2, i, tmp16);
  __syncthreads();
  float o[16];
  #pragma unroll
  for (int j = 0; j < 16; ++j) o[j] = 0.f;
  mm_pass<false>(S1, i, la, o);               // LvT @ La   (B = La regs)
  mm_pass<false>(S2, i, cam, o);              // Lv  @ camTE
  float4* dst = reinterpret_cast<float4*>(out + batch * 256 + (size_t)i * 16);
  #pragma unroll
  for (int c = 0; c < 4; ++c)
    dst[c] = make_float4(o[4*c], o[4*c+1], o[4*c+2], o[4*c+3]);
}

extern "C" void kernel_launch(void* const* d_in, const int* in_sizes, int n_in,
                              void* d_out, int out_size, void* d_ws, size_t ws_size,
                              hipStream_t stream) {
  const float* mu_TE      = (const float*)d_in[0];
  const float* prec_h     = (const float*)d_in[1];
  const float* chol_v     = (const float*)d_in[2];
  const float* chol_h     = (const float*)d_in[3];
  const float* chol_hv    = (const float*)d_in[4];
  const float* chol_v_TE  = (const float*)d_in[5];
  const float* chol_h_TE  = (const float*)d_in[6];
  const float* chol_hv_TE = (const float*)d_in[7];
  const float* chol_amat  = (const float*)d_in[8];
  float* out = (float*)d_out;

  const int B = in_sizes[0] / 32;             // mu_TE is (B, 32)
  gauss_te_wave<<<B / 4, 64, 0, stream>>>(mu_TE, prec_h, chol_v, chol_h, chol_hv,
                                          chol_v_TE, chol_h_TE, chol_hv_TE,
                                          chol_amat, out, B);
}

// Round 3
// 213.521 us; speedup vs baseline: 3.3911x; 1.9904x over previous
//
#include <hip/hip_runtime.h>

// ConvertParamsTEtoParams0TEGaussLayer — broadcast-B matmul version.
// 64-thread blocks = 1 wave = 4 independent batches (16 lanes per batch).
// Lane i holds row i of A and C in registers (all compile-time indexed);
// B operands live in LDS and are read as float4 same-address broadcasts
// within each 16-lane group (4 distinct addresses per wave, slabs skewed
// by 8 banks -> conflict-free). No DPP, no register rotation.
//
// Algebra: Pinv symmetric => prec_h_inv_TE = -(W + W^T), W = Pinv@S@Pinv,
// S = chol_h_TE@chol_h^T + chol_hv_TE@chol_hv^T.
// cinv of unit-lower chol_amat via per-lane-column forward substitution.

constexpr int ROWF  = 20;         // LDS row pitch (16 + 4 pad floats, 80 B, 16B-aligned)
constexpr int BSTR  = 328;        // per-batch slab stride (floats); 328%32=8 -> bank skew
constexpr int SLOTF = 4 * BSTR;   // slot stride (4 batches per wave)

__device__ __forceinline__ void load_rows_g(const float* __restrict__ gsrc,
                                            size_t batch, int i, float (&v)[16]) {
  const float4* s = reinterpret_cast<const float4*>(gsrc + batch * 256 + (size_t)i * 16);
  #pragma unroll
  for (int c = 0; c < 4; ++c) {
    float4 q = s[c];
    v[4*c+0] = q.x; v[4*c+1] = q.y; v[4*c+2] = q.z; v[4*c+3] = q.w;
  }
}

__device__ __forceinline__ void store_rows_l(float* dst, int i, const float (&v)[16]) {
  #pragma unroll
  for (int c = 0; c < 4; ++c)
    reinterpret_cast<float4*>(dst + i * ROWF)[c] =
        make_float4(v[4*c], v[4*c+1], v[4*c+2], v[4*c+3]);
}

// transposed store: dst[j][i] = v[j]  (16 scalar ds_write, consecutive lanes
// -> consecutive banks, conflict-free)
__device__ __forceinline__ void storeT_l(float* dst, int i, const float (&v)[16]) {
  #pragma unroll
  for (int j = 0; j < 16; ++j) dst[j * ROWF + i] = v[j];
}

// column read: v[k] = src[k][i]  (rows of src^T)
__device__ __forceinline__ void load_colsl(const float* src, int i, float (&v)[16]) {
  #pragma unroll
  for (int k = 0; k < 16; ++k) v[k] = src[k * ROWF + i];
}

__device__ __forceinline__ void zero16(float (&v)[16]) {
  #pragma unroll
  for (int j = 0; j < 16; ++j) v[j] = 0.f;
}

// C += A @ B : A rows in regs (a[k] compile-time indexed), B in LDS row-major,
// read as 4x float4 broadcast per k. 256 FMA + 64 ds_read_b128 per pass.
__device__ __forceinline__ void mmB(const float (&a)[16], const float* __restrict__ B,
                                    float (&c)[16]) {
  #pragma unroll
  for (int k = 0; k < 16; ++k) {
    const float4 q0 = *reinterpret_cast<const float4*>(B + k * ROWF + 0);
    const float4 q1 = *reinterpret_cast<const float4*>(B + k * ROWF + 4);
    const float4 q2 = *reinterpret_cast<const float4*>(B + k * ROWF + 8);
    const float4 q3 = *reinterpret_cast<const float4*>(B + k * ROWF + 12);
    c[0]  = fmaf(a[k], q0.x, c[0]);  c[1]  = fmaf(a[k], q0.y, c[1]);
    c[2]  = fmaf(a[k], q0.z, c[2]);  c[3]  = fmaf(a[k], q0.w, c[3]);
    c[4]  = fmaf(a[k], q1.x, c[4]);  c[5]  = fmaf(a[k], q1.y, c[5]);
    c[6]  = fmaf(a[k], q1.z, c[6]);  c[7]  = fmaf(a[k], q1.w, c[7]);
    c[8]  = fmaf(a[k], q2.x, c[8]);  c[9]  = fmaf(a[k], q2.y, c[9]);
    c[10] = fmaf(a[k], q2.z, c[10]); c[11] = fmaf(a[k], q2.w, c[11]);
    c[12] = fmaf(a[k], q3.x, c[12]); c[13] = fmaf(a[k], q3.y, c[13]);
    c[14] = fmaf(a[k], q3.z, c[14]); c[15] = fmaf(a[k], q3.w, c[15]);
  }
}

__global__ __launch_bounds__(64) void gauss_te_wave(
    const float* __restrict__ mu_TE,      // (B, 32)
    const float* __restrict__ prec_h,
    const float* __restrict__ chol_v,
    const float* __restrict__ chol_h,
    const float* __restrict__ chol_hv,
    const float* __restrict__ chol_v_TE,
    const float* __restrict__ chol_h_TE,
    const float* __restrict__ chol_hv_TE,
    const float* __restrict__ chol_amat,
    float* __restrict__ out, int B)
{
  __shared__ __align__(16) float slab[2 * SLOTF];
  const int t = threadIdx.x;
  const int g = t >> 4;                 // batch group within wave (0..3)
  const int i = t & 15;                 // row owned by this lane
  const size_t batch = (size_t)blockIdx.x * 4 + g;

  float* SA = slab + 0 * SLOTF + g * BSTR;
  float* SB = slab + 1 * SLOTF + g * BSTR;

  // ---- muv_TE passthrough ----
  out[(size_t)B * 256 + batch * 16 + i] = mu_TE[batch * 32 + i];

  // ---- Pinv = inv(prec_h): in-place GJ, rows in regs, pivot row via LDS ----
  float p[16];
  load_rows_g(prec_h, batch, i, p);
  #pragma unroll
  for (int k = 0; k < 16; ++k) {
    float* buf = SA + (k & 1) * 16;     // double-buffered broadcast row
    if (i == k) {
      const float piv = 1.0f / p[k];
      float tt[16];
      #pragma unroll
      for (int c = 0; c < 16; ++c) tt[c] = p[c] * piv;
      tt[k] = piv;
      #pragma unroll
      for (int c = 0; c < 4; ++c)
        reinterpret_cast<float4*>(buf)[c] =
            make_float4(tt[4*c], tt[4*c+1], tt[4*c+2], tt[4*c+3]);
    }
    __syncthreads();
    float br[16];
    #pragma unroll
    for (int c = 0; c < 4; ++c) {
      float4 q = reinterpret_cast<const float4*>(buf)[c];
      br[4*c+0] = q.x; br[4*c+1] = q.y; br[4*c+2] = q.z; br[4*c+3] = q.w;
    }
    if (i != k) {
      const float f = p[k];
      #pragma unroll
      for (int c = 0; c < 16; ++c) p[c] = fmaf(-f, br[c], p[c]);
      p[k] = -f * br[k];
    } else {
      #pragma unroll
      for (int c = 0; c < 16; ++c) p[c] = br[c];
    }
    __syncthreads();
  }
  // SA free; p = Pinv rows.

  // ---- S = LhT@Lh^T + HvT@Hv^T ----
  float ta[16], tb[16];
  load_rows_g(chol_h, batch, i, tb);          // Lh rows
  storeT_l(SB, i, tb);                        // SB = Lh^T
  load_rows_g(chol_h_TE, batch, i, ta);       // LhT rows
  store_rows_l(SA, i, p);                     // SA = Pinv
  __syncthreads();
  float S[16]; zero16(S);
  mmB(ta, SB, S);                             // S = LhT @ Lh^T

  float hv[16], hvT[16];
  load_rows_g(chol_hv, batch, i, hv);
  load_rows_g(chol_hv_TE, batch, i, hvT);
  __syncthreads();                            // SB reads done before overwrite
  storeT_l(SB, i, hv);                        // SB = Hv^T
  __syncthreads();
  mmB(hvT, SB, S);                            // S += HvT @ Hv^T

  // ---- W = (Pinv@S)@Pinv ; PiTE = -(W + W^T) ----
  __syncthreads();
  store_rows_l(SB, i, S);                     // SB = S
  __syncthreads();
  float w1[16]; zero16(w1);
  mmB(p, SB, w1);                             // W1 = Pinv @ S
  float w[16]; zero16(w);
  mmB(w1, SA, w);                             // W = W1 @ Pinv
  __syncthreads();
  store_rows_l(SB, i, w);                     // SB = W
  __syncthreads();
  float pite[16];
  {
    float wt[16];
    load_colsl(SB, i, wt);                    // rows of W^T
    #pragma unroll
    for (int j = 0; j < 16; ++j) pite[j] = -(w[j] + wt[j]);
  }

  // ---- M1 = Pinv@Hv ; M23 = PiTE@Hv + Pinv@HvT ----
  __syncthreads();                            // W^T col reads done
  store_rows_l(SB, i, hv);                    // SB = Hv (rows)
  __syncthreads();
  float m1[16]; zero16(m1);
  float m23[16]; zero16(m23);
  mmB(p, SB, m1);                             // M1 = Pinv@Hv
  mmB(pite, SB, m23);                         // M2 = PiTE@Hv
  __syncthreads();
  store_rows_l(SA, i, hvT);                   // SA = HvT (Pinv-as-B dead)
  __syncthreads();
  mmB(p, SA, m23);                            // += M3 = Pinv@HvT

  // ---- amatTE = -(HvT^T@M1 + Hv^T@M23) ----
  float a1[16], a2[16];
  load_colsl(SA, i, a1);                      // rows of HvT^T
  load_colsl(SB, i, a2);                      // rows of Hv^T
  __syncthreads();
  store_rows_l(SA, i, m1);                    // SA = M1
  store_rows_l(SB, i, m23);                   // SB = M23
  __syncthreads();
  float am[16]; zero16(am);
  mmB(a1, SA, am);                            // HvT^T @ M1
  mmB(a2, SB, am);                            // Hv^T  @ M23
  #pragma unroll
  for (int j = 0; j < 16; ++j) am[j] = -am[j];

  // ---- cinv: forward substitution, lane i = column i (diag = 1) ----
  float la[16];
  load_rows_g(chol_amat, batch, i, la);
  __syncthreads();                            // SA/SB mmB reads done
  store_rows_l(SA, i, la);                    // SA = La
  __syncthreads();
  float x[16];                                // x[r] = cinv[r][i]
  #pragma unroll
  for (int r = 0; r < 16; ++r) {
    float s = (i == r) ? 1.0f : 0.0f;
    #pragma unroll
    for (int k = 0; k < 16; ++k)
      if (k < r) s = fmaf(-SA[r * ROWF + k], x[k], s);   // broadcast reads
    x[r] = s;
  }

  // ---- Y = amatTE@cinv^T ; arg = cinv@Y ; masked = arg*phi ----
  __syncthreads();
  store_rows_l(SB, i, x);                     // SB = cinv^T (row i = col i of cinv)
  __syncthreads();
  float y[16]; zero16(y);
  mmB(am, SB, y);                             // Y = amatTE @ cinv^T
  float ac[16];
  load_colsl(SB, i, ac);                      // rows of cinv
  __syncthreads();
  store_rows_l(SB, i, y);                     // SB = Y
  __syncthreads();
  float arg[16]; zero16(arg);
  mmB(ac, SB, arg);                           // arg = cinv @ Y
  #pragma unroll
  for (int j = 0; j < 16; ++j)                // phi: strict-lower 1, diag 0.5, upper 0
    arg[j] = (j < i) ? arg[j] : ((j == i) ? 0.5f * arg[j] : 0.0f);

  // ---- camTE = La @ masked ----
  __syncthreads();
  store_rows_l(SB, i, arg);                   // SB = masked
  __syncthreads();
  float cam[16]; zero16(cam);
  mmB(la, SB, cam);

  // ---- out = LvT@La + Lv@camTE ----
  float o[16]; zero16(o);
  load_rows_g(chol_v_TE, batch, i, ta);       // LvT rows
  mmB(ta, SA, o);                             // LvT @ La   (SA = La still)
  __syncthreads();
  store_rows_l(SB, i, cam);                   // SB = camTE
  __syncthreads();
  load_rows_g(chol_v, batch, i, tb);          // Lv rows
  mmB(tb, SB, o);                             // Lv @ camTE
  float4* dst = reinterpret_cast<float4*>(out + batch * 256 + (size_t)i * 16);
  #pragma unroll
  for (int c = 0; c < 4; ++c)
    dst[c] = make_float4(o[4*c], o[4*c+1], o[4*c+2], o[4*c+3]);
}

extern "C" void kernel_launch(void* const* d_in, const int* in_sizes, int n_in,
                              void* d_out, int out_size, void* d_ws, size_t ws_size,
                              hipStream_t stream) {
  const float* mu_TE      = (const float*)d_in[0];
  const float* prec_h     = (const float*)d_in[1];
  const float* chol_v     = (const float*)d_in[2];
  const float* chol_h     = (const float*)d_in[3];
  const float* chol_hv    = (const float*)d_in[4];
  const float* chol_v_TE  = (const float*)d_in[5];
  const float* chol_h_TE  = (const float*)d_in[6];
  const float* chol_hv_TE = (const float*)d_in[7];
  const float* chol_amat  = (const float*)d_in[8];
  float* out = (float*)d_out;

  const int B = in_sizes[0] / 32;             // mu_TE is (B, 32)
  gauss_te_wave<<<B / 4, 64, 0, stream>>>(mu_TE, prec_h, chol_v, chol_h, chol_hv,
                                          chol_v_TE, chol_h_TE, chol_hv_TE,
                                          chol_amat, out, B);
}

// Round 4
// 147.847 us; speedup vs baseline: 4.8974x; 1.4442x over previous
//
#include <hip/hip_runtime.h>

// ConvertParamsTEtoParams0TEGaussLayer — tile4 + packed-f16 fdot2 version.
// 64-thread blocks = 1 wave = 4 batches (16 lanes each). Lane (p,q) owns the
// 4x4 tile C[4p..4p+3][4q..4q+3] of every matrix. Matmul operands live in LDS
// as f16 pairs packed along K: u32 = (X[.][2kp], X[.][2kp+1]). Per K-pair each
// lane does 2 ds_read_b128 + 16 v_dot2_f32_f16 (f32 accumulate).
//
// Layout duality (transposes are free):
//   RP(X)[kp][i] = pack(X[i][2kp], X[i][2kp+1])  == A-role of X, B-role of X^T
//   CP(X)[kp][j] = pack(X[2kp][j], X[2kp+1][j])  == B-role of X, A-role of X^T
// Algebra: S = LhT@Lh^T + HvT@Hv^T; W = Pinv@S@Pinv; PiTE = -(W+W^T);
// M1 = Pinv@Hv; U' = (W+W^T)@Hv; Z = HvT^T@M1; V2' = Hv^T@U';
// amatTE = V2' - Z - Z^T (assembled in packed space inside the Y pass).
// GJ inverse (f32) in tile layout; unit-lower forward substitution (f32) from
// packed CP(La).

typedef _Float16 h2 __attribute__((ext_vector_type(2)));

constexpr int PITCH = 20;           // u32 per kp-row (16 + 4 pad; keeps 16B align, conflict-free packs)
constexpr int IMG   = 8 * PITCH;    // 160 u32 per packed image
constexpr int NSLOT = 7;
constexpr int ARENA = NSLOT * IMG;  // f32 arena offset (1120)
constexpr int BSTR  = 1192;         // per-batch stride in u32 (== 8 mod 32: bank skew)

__device__ __forceinline__ unsigned int pkf(float a, float b) {
  return __builtin_bit_cast(unsigned int, __builtin_amdgcn_cvt_pkrtz(a, b));
}
__device__ __forceinline__ unsigned int h2add(unsigned int a, unsigned int b) {
  return __builtin_bit_cast(unsigned int,
      (h2)(__builtin_bit_cast(h2, a) + __builtin_bit_cast(h2, b)));
}
__device__ __forceinline__ unsigned int h2sub3(unsigned int a, unsigned int b, unsigned int c) {
  return __builtin_bit_cast(unsigned int,
      (h2)(__builtin_bit_cast(h2, a) - __builtin_bit_cast(h2, b) - __builtin_bit_cast(h2, c)));
}
__device__ __forceinline__ float fd2(unsigned int a, unsigned int b, float c) {
#if __has_builtin(__builtin_amdgcn_fdot2)
  return __builtin_amdgcn_fdot2(__builtin_bit_cast(h2, a), __builtin_bit_cast(h2, b), c, false);
#else
  h2 ha = __builtin_bit_cast(h2, a), hb = __builtin_bit_cast(h2, b);
  return c + (float)ha.x * (float)hb.x + (float)ha.y * (float)hb.y;
#endif
}
__device__ __forceinline__ float dpp_swap1(float v) {  // lane c <-> lane c^1 (quad_perm 1,0,3,2)
  return __int_as_float(__builtin_amdgcn_update_dpp(
      0, __float_as_int(v), 0xB1, 0xF, 0xF, false));
}

__device__ __forceinline__ void zero16(float (&v)[16]) {
  #pragma unroll
  for (int j = 0; j < 16; ++j) v[j] = 0.f;
}

__device__ __forceinline__ void ldtile(const float* __restrict__ g, size_t batch,
                                       int p, int q, float (&c)[16]) {
  const float* base = g + batch * 256 + p * 64 + q * 4;
  #pragma unroll
  for (int r = 0; r < 4; ++r) {
    float4 v = *reinterpret_cast<const float4*>(base + r * 16);
    c[r*4+0] = v.x; c[r*4+1] = v.y; c[r*4+2] = v.z; c[r*4+3] = v.w;
  }
}

// RP store from tile: img[2q+b][4p+r] = pack(c[r][2b*?]) — pairs adjacent cols.
__device__ __forceinline__ void storeRP(unsigned int* img, int p, int q, const float (&c)[16]) {
  #pragma unroll
  for (int r = 0; r < 4; ++r) {
    img[(2*q  ) * PITCH + 4*p + r] = pkf(c[r*4+0], c[r*4+1]);
    img[(2*q+1) * PITCH + 4*p + r] = pkf(c[r*4+2], c[r*4+3]);
  }
}
// CP store from tile: img[2p+b][4q+j] = pack over adjacent rows.
__device__ __forceinline__ void storeCP(unsigned int* img, int p, int q, const float (&c)[16]) {
  uint4 w0, w1;
  w0.x = pkf(c[0],  c[4]);  w0.y = pkf(c[1],  c[5]);
  w0.z = pkf(c[2],  c[6]);  w0.w = pkf(c[3],  c[7]);
  w1.x = pkf(c[8],  c[12]); w1.y = pkf(c[9],  c[13]);
  w1.z = pkf(c[10], c[14]); w1.w = pkf(c[11], c[15]);
  *reinterpret_cast<uint4*>(img + (2*p  ) * PITCH + 4*q) = w0;
  *reinterpret_cast<uint4*>(img + (2*p+1) * PITCH + 4*q) = w1;
}

// c[r*4+j] += sum_k A[4p+r][k] * B[k][4q+j]; A-image RP-style, B-image CP-style.
__device__ __forceinline__ void mm1(const unsigned int* __restrict__ A,
                                    const unsigned int* __restrict__ Bm,
                                    int p4, int q4, float (&c)[16]) {
  #pragma unroll
  for (int kp = 0; kp < 8; ++kp) {
    uint4 av = *reinterpret_cast<const uint4*>(A  + kp * PITCH + p4);
    uint4 bv = *reinterpret_cast<const uint4*>(Bm + kp * PITCH + q4);
    const unsigned int ar[4] = {av.x, av.y, av.z, av.w};
    const unsigned int br[4] = {bv.x, bv.y, bv.z, bv.w};
    #pragma unroll
    for (int r = 0; r < 4; ++r)
      #pragma unroll
      for (int j = 0; j < 4; ++j)
        c[r*4+j] = fd2(ar[r], br[j], c[r*4+j]);
  }
}
// A = A0 + A1 (packed f16 add on the fly)
__device__ __forceinline__ void mm2(const unsigned int* __restrict__ A0,
                                    const unsigned int* __restrict__ A1,
                                    const unsigned int* __restrict__ Bm,
                                    int p4, int q4, float (&c)[16]) {
  #pragma unroll
  for (int kp = 0; kp < 8; ++kp) {
    uint4 a0 = *reinterpret_cast<const uint4*>(A0 + kp * PITCH + p4);
    uint4 a1 = *reinterpret_cast<const uint4*>(A1 + kp * PITCH + p4);
    uint4 bv = *reinterpret_cast<const uint4*>(Bm + kp * PITCH + q4);
    const unsigned int ar[4] = {h2add(a0.x, a1.x), h2add(a0.y, a1.y),
                                h2add(a0.z, a1.z), h2add(a0.w, a1.w)};
    const unsigned int br[4] = {bv.x, bv.y, bv.z, bv.w};
    #pragma unroll
    for (int r = 0; r < 4; ++r)
      #pragma unroll
      for (int j = 0; j < 4; ++j)
        c[r*4+j] = fd2(ar[r], br[j], c[r*4+j]);
  }
}
// A = A0 - A1 - A2
__device__ __forceinline__ void mm3(const unsigned int* __restrict__ A0,
                                    const unsigned int* __restrict__ A1,
                                    const unsigned int* __restrict__ A2,
                                    const unsigned int* __restrict__ Bm,
                                    int p4, int q4, float (&c)[16]) {
  #pragma unroll
  for (int kp = 0; kp < 8; ++kp) {
    uint4 a0 = *reinterpret_cast<const uint4*>(A0 + kp * PITCH + p4);
    uint4 a1 = *reinterpret_cast<const uint4*>(A1 + kp * PITCH + p4);
    uint4 a2 = *reinterpret_cast<const uint4*>(A2 + kp * PITCH + p4);
    uint4 bv = *reinterpret_cast<const uint4*>(Bm + kp * PITCH + q4);
    const unsigned int ar[4] = {h2sub3(a0.x, a1.x, a2.x), h2sub3(a0.y, a1.y, a2.y),
                                h2sub3(a0.z, a1.z, a2.z), h2sub3(a0.w, a1.w, a2.w)};
    const unsigned int br[4] = {bv.x, bv.y, bv.z, bv.w};
    #pragma unroll
    for (int r = 0; r < 4; ++r)
      #pragma unroll
      for (int j = 0; j < 4; ++j)
        c[r*4+j] = fd2(ar[r], br[j], c[r*4+j]);
  }
}

__global__ __launch_bounds__(64) void gauss_te_pk(
    const float* __restrict__ mu_TE,
    const float* __restrict__ prec_h,
    const float* __restrict__ chol_v,
    const float* __restrict__ chol_h,
    const float* __restrict__ chol_hv,
    const float* __restrict__ chol_v_TE,
    const float* __restrict__ chol_h_TE,
    const float* __restrict__ chol_hv_TE,
    const float* __restrict__ chol_amat,
    float* __restrict__ out, int B)
{
  __shared__ __align__(16) unsigned int slab[4 * BSTR];
  const int t = threadIdx.x;
  const int g = t >> 4;                   // batch group in wave
  const int l = t & 15;                   // lane within group
  const int p = l >> 2, q = l & 3;        // tile coords
  const int p4 = 4 * p, q4 = 4 * q;
  const size_t batch = (size_t)blockIdx.x * 4 + g;

  unsigned int* U = slab + g * BSTR;
  unsigned int* P0 = U;            unsigned int* P1 = U + 1*IMG;
  unsigned int* P2 = U + 2*IMG;    unsigned int* P3 = U + 3*IMG;
  unsigned int* P4 = U + 4*IMG;    unsigned int* P5 = U + 5*IMG;
  unsigned int* P6 = U + 6*IMG;
  float* fa = reinterpret_cast<float*>(U + ARENA);   // 64 floats: fcol[2][16], brow[2][16]
  float* fcol = fa;
  float* brow = fa + 32;

  // ---- muv_TE passthrough ----
  out[(size_t)B * 256 + batch * 16 + l] = mu_TE[batch * 32 + l];

  // ---- input loads + packs ----
  float tt[16];
  ldtile(chol_h, batch, p, q, tt);     storeRP(P0, p, q, tt);                         // RP(Lh)
  ldtile(chol_h_TE, batch, p, q, tt);  storeRP(P1, p, q, tt);                         // RP(LhT)
  ldtile(chol_hv, batch, p, q, tt);    storeRP(P2, p, q, tt); storeCP(P3, p, q, tt);  // RP/CP(Hv)
  ldtile(chol_hv_TE, batch, p, q, tt); storeRP(P4, p, q, tt); storeCP(P5, p, q, tt);  // RP/CP(HvT)

  // ---- Pinv = inv(prec_h): tile-layout Gauss-Jordan, f32 ----
  float pt[16];
  ldtile(prec_h, batch, p, q, pt);
  #pragma unroll
  for (int k = 0; k < 16; ++k) {
    const int kb = k >> 2, kc = k & 3, sel = (k & 1) * 16;
    if (q == kb) {   // column-k owners publish their col-k chunk
      *reinterpret_cast<float4*>(fcol + sel + p4) =
          make_float4(pt[0*4+kc], pt[1*4+kc], pt[2*4+kc], pt[3*4+kc]);
    }
    __syncthreads();
    if (p == kb) {   // pivot-row owners publish the scaled pivot row
      const float rinv = 1.0f / fcol[sel + k];
      float sv[4];
      #pragma unroll
      for (int j = 0; j < 4; ++j) sv[j] = pt[kc*4+j] * rinv;
      if (q == kb) sv[kc] = rinv;
      *reinterpret_cast<float4*>(brow + sel + q4) = make_float4(sv[0], sv[1], sv[2], sv[3]);
    }
    __syncthreads();
    float4 f4 = *reinterpret_cast<const float4*>(fcol + sel + p4);
    float4 b4 = *reinterpret_cast<const float4*>(brow + sel + q4);
    const float fr[4] = {f4.x, f4.y, f4.z, f4.w};
    const float br[4] = {b4.x, b4.y, b4.z, b4.w};
    #pragma unroll
    for (int r = 0; r < 4; ++r) {
      const bool isPivRow = (p == kb) && (r == kc);
      #pragma unroll
      for (int j = 0; j < 4; ++j) {
        float base = pt[r*4+j];
        if (q == kb && j == kc) base = 0.f;       // col-k entry -> -f*rinv
        const float nv = base - fr[r] * br[j];
        pt[r*4+j] = isPivRow ? br[j] : nv;
      }
    }
  }
  storeRP(P6, p, q, pt);    // RP(Pinv) (= CP by symmetry)
  __syncthreads();

  float c[16];

  // ---- S = LhT@Lh^T + HvT@Hv^T ----
  zero16(c);
  mm1(P1, P0, p4, q4, c);             // LhT @ Lh^T
  mm1(P4, P2, p4, q4, c);             // HvT @ Hv^T
  __syncthreads();
  storeCP(P0, p, q, c);               // CP(S)
  __syncthreads();

  // ---- W1 = Pinv@S ----
  zero16(c);
  mm1(P6, P0, p4, q4, c);
  __syncthreads();
  storeRP(P1, p, q, c);               // RP(W1)
  __syncthreads();

  // ---- W = W1@Pinv ----
  zero16(c);
  mm1(P1, P6, p4, q4, c);
  __syncthreads();
  storeRP(P2, p, q, c); storeCP(P4, p, q, c);   // RP/CP(W)
  __syncthreads();

  // ---- M1 = Pinv@Hv ----
  zero16(c);
  mm1(P6, P3, p4, q4, c);
  __syncthreads();
  storeCP(P0, p, q, c);               // CP(M1)
  __syncthreads();

  // ---- U' = (W+W^T)@Hv ----
  zero16(c);
  mm2(P2, P4, P3, p4, q4, c);
  __syncthreads();
  storeCP(P6, p, q, c);               // CP(U')
  __syncthreads();

  // ---- Z = HvT^T@M1 ----
  zero16(c);
  mm1(P5, P0, p4, q4, c);             // A-role of HvT^T = CP(HvT)
  __syncthreads();
  storeRP(P2, p, q, c); storeCP(P4, p, q, c);   // RP/CP(Z)
  __syncthreads();

  // ---- V2' = Hv^T@U' ----
  zero16(c);
  mm1(P3, P6, p4, q4, c);             // A-role of Hv^T = CP(Hv)
  __syncthreads();
  storeRP(P5, p, q, c);               // RP(V2')
  __syncthreads();

  // ---- La load + packs ----
  float la[16];
  ldtile(chol_amat, batch, p, q, la);
  storeRP(P0, p, q, la);              // RP(La)
  storeCP(P3, p, q, la);              // CP(La)
  __syncthreads();

  // ---- cinv: forward substitution (lane l = column l), reads CP(La) ----
  float x[16];
  #pragma unroll
  for (int kp = 0; kp < 8; ++kp) {
    const int r0 = 2 * kp, r1 = r0 + 1;
    float a0 = 0.f, a1 = 0.f, h10 = 0.f;
    #pragma unroll
    for (int c2 = 0; c2 <= kp / 2; ++c2) {
      uint4 cv = *reinterpret_cast<const uint4*>(P3 + kp * PITCH + 4 * c2);
      const unsigned int cw[4] = {cv.x, cv.y, cv.z, cv.w};
      #pragma unroll
      for (int cc = 0; cc < 4; ++cc) {
        const int j = 4 * c2 + cc;
        h2 hp = __builtin_bit_cast(h2, cw[cc]);
        if (j < r0) a0 = fmaf(-(float)hp.x, x[j], a0);
        if (j < r0) a1 = fmaf(-(float)hp.y, x[j], a1);
        if (j == r0) h10 = (float)hp.y;       // La[r1][r0]
      }
    }
    x[r0] = ((l == r0) ? 1.f : 0.f) + a0;
    x[r1] = ((l == r1) ? 1.f : 0.f) + a1 - h10 * x[r0];
  }
  // RP(cinv)[kp][i] = pack(x_{2kp}[i], x_{2kp+1}[i]) — even lanes write row l/2
  {
    float xp[16];
    #pragma unroll
    for (int j = 0; j < 16; ++j) xp[j] = dpp_swap1(x[j]);
    if ((l & 1) == 0) {
      unsigned int* dst = P6 + (l >> 1) * PITCH;
      #pragma unroll
      for (int c4 = 0; c4 < 4; ++c4) {
        uint4 w;
        w.x = pkf(x[4*c4+0], xp[4*c4+0]); w.y = pkf(x[4*c4+1], xp[4*c4+1]);
        w.z = pkf(x[4*c4+2], xp[4*c4+2]); w.w = pkf(x[4*c4+3], xp[4*c4+3]);
        *reinterpret_cast<uint4*>(dst + 4*c4) = w;
      }
    }
  }
  __syncthreads();

  // ---- Y = amatTE @ cinv^T, amatTE = V2' - Z - Z^T (packed on the fly) ----
  zero16(c);
  mm3(P5, P2, P4, P6, p4, q4, c);     // B-role of cinv^T = RP(cinv)
  __syncthreads();
  storeCP(P1, p, q, c);               // CP(Y)
  __syncthreads();

  // ---- arg = cinv@Y, then phi mask ----
  zero16(c);
  mm1(P6, P1, p4, q4, c);
  #pragma unroll
  for (int r = 0; r < 4; ++r)
    #pragma unroll
    for (int j = 0; j < 4; ++j) {
      const int gi = p4 + r, gj = q4 + j;
      c[r*4+j] = (gi > gj) ? c[r*4+j] : ((gi == gj) ? 0.5f * c[r*4+j] : 0.f);
    }
  __syncthreads();
  storeCP(P2, p, q, c);               // CP(masked arg)
  __syncthreads();

  // ---- camTE = La @ masked ----
  zero16(c);
  mm1(P0, P2, p4, q4, c);
  __syncthreads();
  storeCP(P4, p, q, c);               // CP(cam)
  __syncthreads();

  // ---- LvT, Lv loads ----
  ldtile(chol_v_TE, batch, p, q, tt); storeRP(P5, p, q, tt);   // RP(LvT)
  ldtile(chol_v, batch, p, q, tt);    storeRP(P1, p, q, tt);   // RP(Lv)
  __syncthreads();

  // ---- out = LvT@La + Lv@camTE ----
  zero16(c);
  mm1(P5, P3, p4, q4, c);             // LvT @ La   (CP(La) still live in P3)
  mm1(P1, P4, p4, q4, c);             // Lv @ camTE
  {
    float* base = out + batch * 256 + p * 64 + q * 4;
    #pragma unroll
    for (int r = 0; r < 4; ++r)
      *reinterpret_cast<float4*>(base + r * 16) =
          make_float4(c[r*4+0], c[r*4+1], c[r*4+2], c[r*4+3]);
  }
}

extern "C" void kernel_launch(void* const* d_in, const int* in_sizes, int n_in,
                              void* d_out, int out_size, void* d_ws, size_t ws_size,
                              hipStream_t stream) {
  const float* mu_TE      = (const float*)d_in[0];
  const float* prec_h     = (const float*)d_in[1];
  const float* chol_v     = (const float*)d_in[2];
  const float* chol_h     = (const float*)d_in[3];
  const float* chol_hv    = (const float*)d_in[4];
  const float* chol_v_TE  = (const float*)d_in[5];
  const float* chol_h_TE  = (const float*)d_in[6];
  const float* chol_hv_TE = (const float*)d_in[7];
  const float* chol_amat  = (const float*)d_in[8];
  float* out = (float*)d_out;

  const int B = in_sizes[0] / 32;     // mu_TE is (B, 32)
  gauss_te_pk<<<B / 4, 64, 0, stream>>>(mu_TE, prec_h, chol_v, chol_h, chol_hv,
                                        chol_v_TE, chol_h_TE, chol_hv_TE,
                                        chol_amat, out, B);
}

// Round 5
// 146.840 us; speedup vs baseline: 4.9310x; 1.0069x over previous
//
#include <hip/hip_runtime.h>

// ConvertParamsTEtoParams0TEGaussLayer — tile4 + packed-f16 fdot2, 6-slot LDS.
// 64-thread blocks = 1 wave = 4 batches (16 lanes each). Lane (p,q) owns the
// 4x4 tile C[4p..4p+3][4q..4q+3]. Operands in LDS as f16 pairs packed along K.
//
//   RP(X)[kp][i] = pack(X[i][2kp], X[i][2kp+1])  == A-role of X, B-role of X^T
//   CP(X)[kp][j] = pack(X[2kp][j], X[2kp+1][j])  == B-role of X, A-role of X^T
//
// LDS budget: 6 images x 128 u32 + 8 pad = 776 u32/batch, 12416 B/block
// -> 13 blocks/CU (was 8). GJ broadcast arena lives in slot P5 (dead there).
// Slot lifetime schedule (all stores land in just-dead slots):
//   P0: RP(Lh) -> CP(S) -> RP(W) -> RP(Z) -> CP(Y) -> RP(LvT)
//   P1: RP(LhT) -> CP(Hv) -> RP(La)
//   P2: RP(Hv) -> CP(HvT) -> CP(La)
//   P3: RP(HvT) -> RP(W1) -> CP(M1) -> RP(V2') -> CP(cam)
//   P4: RP(Pinv) -> CP(U') -> RP(cinv) -> RP(Lv)
//   P5: [GJ arena] -> CP(W) -> CP(Z) -> CP(arg)

typedef _Float16 h2 __attribute__((ext_vector_type(2)));

constexpr int PITCH = 16;           // u32 per kp-row (no pad; group skew handles banks)
constexpr int IMG   = 8 * PITCH;    // 128 u32 per packed image
constexpr int NSLOT = 6;
constexpr int BSTR  = NSLOT * IMG + 8;  // 776 u32; 776 % 32 == 8 -> bank skew per group

__device__ __forceinline__ unsigned int pkf(float a, float b) {
  return __builtin_bit_cast(unsigned int, __builtin_amdgcn_cvt_pkrtz(a, b));
}
__device__ __forceinline__ unsigned int h2add(unsigned int a, unsigned int b) {
  return __builtin_bit_cast(unsigned int,
      (h2)(__builtin_bit_cast(h2, a) + __builtin_bit_cast(h2, b)));
}
__device__ __forceinline__ unsigned int h2sub3(unsigned int a, unsigned int b, unsigned int c) {
  return __builtin_bit_cast(unsigned int,
      (h2)(__builtin_bit_cast(h2, a) - __builtin_bit_cast(h2, b) - __builtin_bit_cast(h2, c)));
}
__device__ __forceinline__ float fd2(unsigned int a, unsigned int b, float c) {
#if __has_builtin(__builtin_amdgcn_fdot2)
  return __builtin_amdgcn_fdot2(__builtin_bit_cast(h2, a), __builtin_bit_cast(h2, b), c, false);
#else
  h2 ha = __builtin_bit_cast(h2, a), hb = __builtin_bit_cast(h2, b);
  return c + (float)ha.x * (float)hb.x + (float)ha.y * (float)hb.y;
#endif
}
__device__ __forceinline__ float dpp_swap1(float v) {  // lane c <-> c^1 (quad_perm 1,0,3,2)
  return __int_as_float(__builtin_amdgcn_update_dpp(
      0, __float_as_int(v), 0xB1, 0xF, 0xF, false));
}

__device__ __forceinline__ void zero16(float (&v)[16]) {
  #pragma unroll
  for (int j = 0; j < 16; ++j) v[j] = 0.f;
}

__device__ __forceinline__ void ldtile(const float* __restrict__ g, size_t batch,
                                       int p, int q, float (&c)[16]) {
  const float* base = g + batch * 256 + p * 64 + q * 4;
  #pragma unroll
  for (int r = 0; r < 4; ++r) {
    float4 v = *reinterpret_cast<const float4*>(base + r * 16);
    c[r*4+0] = v.x; c[r*4+1] = v.y; c[r*4+2] = v.z; c[r*4+3] = v.w;
  }
}

__device__ __forceinline__ void storeRP(unsigned int* img, int p, int q, const float (&c)[16]) {
  #pragma unroll
  for (int r = 0; r < 4; ++r) {
    img[(2*q  ) * PITCH + 4*p + r] = pkf(c[r*4+0], c[r*4+1]);
    img[(2*q+1) * PITCH + 4*p + r] = pkf(c[r*4+2], c[r*4+3]);
  }
}
// CP pack into registers (8 u32): w[0..3] = row 2p chunk, w[4..7] = row 2p+1 chunk
__device__ __forceinline__ void packCP(const float (&c)[16], unsigned int (&w)[8]) {
  w[0] = pkf(c[0],  c[4]);  w[1] = pkf(c[1],  c[5]);
  w[2] = pkf(c[2],  c[6]);  w[3] = pkf(c[3],  c[7]);
  w[4] = pkf(c[8],  c[12]); w[5] = pkf(c[9],  c[13]);
  w[6] = pkf(c[10], c[14]); w[7] = pkf(c[11], c[15]);
}
__device__ __forceinline__ void writeCPregs(unsigned int* img, int p, int q,
                                            const unsigned int (&w)[8]) {
  *reinterpret_cast<uint4*>(img + (2*p  ) * PITCH + 4*q) = make_uint4(w[0], w[1], w[2], w[3]);
  *reinterpret_cast<uint4*>(img + (2*p+1) * PITCH + 4*q) = make_uint4(w[4], w[5], w[6], w[7]);
}
__device__ __forceinline__ void storeCP(unsigned int* img, int p, int q, const float (&c)[16]) {
  unsigned int w[8];
  packCP(c, w);
  writeCPregs(img, p, q, w);
}

// c[r*4+j] += sum_k A[4p+r][k] * B[k][4q+j]; A RP-style, B CP-style.
__device__ __forceinline__ void mm1(const unsigned int* __restrict__ A,
                                    const unsigned int* __restrict__ Bm,
                                    int p4, int q4, float (&c)[16]) {
  #pragma unroll
  for (int kp = 0; kp < 8; ++kp) {
    uint4 av = *reinterpret_cast<const uint4*>(A  + kp * PITCH + p4);
    uint4 bv = *reinterpret_cast<const uint4*>(Bm + kp * PITCH + q4);
    const unsigned int ar[4] = {av.x, av.y, av.z, av.w};
    const unsigned int br[4] = {bv.x, bv.y, bv.z, bv.w};
    #pragma unroll
    for (int r = 0; r < 4; ++r)
      #pragma unroll
      for (int j = 0; j < 4; ++j)
        c[r*4+j] = fd2(ar[r], br[j], c[r*4+j]);
  }
}
__device__ __forceinline__ void mm2(const unsigned int* __restrict__ A0,
                                    const unsigned int* __restrict__ A1,
                                    const unsigned int* __restrict__ Bm,
                                    int p4, int q4, float (&c)[16]) {
  #pragma unroll
  for (int kp = 0; kp < 8; ++kp) {
    uint4 a0 = *reinterpret_cast<const uint4*>(A0 + kp * PITCH + p4);
    uint4 a1 = *reinterpret_cast<const uint4*>(A1 + kp * PITCH + p4);
    uint4 bv = *reinterpret_cast<const uint4*>(Bm + kp * PITCH + q4);
    const unsigned int ar[4] = {h2add(a0.x, a1.x), h2add(a0.y, a1.y),
                                h2add(a0.z, a1.z), h2add(a0.w, a1.w)};
    const unsigned int br[4] = {bv.x, bv.y, bv.z, bv.w};
    #pragma unroll
    for (int r = 0; r < 4; ++r)
      #pragma unroll
      for (int j = 0; j < 4; ++j)
        c[r*4+j] = fd2(ar[r], br[j], c[r*4+j]);
  }
}
__device__ __forceinline__ void mm3(const unsigned int* __restrict__ A0,
                                    const unsigned int* __restrict__ A1,
                                    const unsigned int* __restrict__ A2,
                                    const unsigned int* __restrict__ Bm,
                                    int p4, int q4, float (&c)[16]) {
  #pragma unroll
  for (int kp = 0; kp < 8; ++kp) {
    uint4 a0 = *reinterpret_cast<const uint4*>(A0 + kp * PITCH + p4);
    uint4 a1 = *reinterpret_cast<const uint4*>(A1 + kp * PITCH + p4);
    uint4 a2 = *reinterpret_cast<const uint4*>(A2 + kp * PITCH + p4);
    uint4 bv = *reinterpret_cast<const uint4*>(Bm + kp * PITCH + q4);
    const unsigned int ar[4] = {h2sub3(a0.x, a1.x, a2.x), h2sub3(a0.y, a1.y, a2.y),
                                h2sub3(a0.z, a1.z, a2.z), h2sub3(a0.w, a1.w, a2.w)};
    const unsigned int br[4] = {bv.x, bv.y, bv.z, bv.w};
    #pragma unroll
    for (int r = 0; r < 4; ++r)
      #pragma unroll
      for (int j = 0; j < 4; ++j)
        c[r*4+j] = fd2(ar[r], br[j], c[r*4+j]);
  }
}

__global__ __launch_bounds__(64, 4) void gauss_te_pk6(
    const float* __restrict__ mu_TE,
    const float* __restrict__ prec_h,
    const float* __restrict__ chol_v,
    const float* __restrict__ chol_h,
    const float* __restrict__ chol_hv,
    const float* __restrict__ chol_v_TE,
    const float* __restrict__ chol_h_TE,
    const float* __restrict__ chol_hv_TE,
    const float* __restrict__ chol_amat,
    float* __restrict__ out, int B)
{
  __shared__ __align__(16) unsigned int slab[4 * BSTR];
  const int t = threadIdx.x;
  const int g = t >> 4;
  const int l = t & 15;
  const int p = l >> 2, q = l & 3;
  const int p4 = 4 * p, q4 = 4 * q;
  const size_t batch = (size_t)blockIdx.x * 4 + g;

  unsigned int* U = slab + g * BSTR;
  unsigned int* P0 = U;            unsigned int* P1 = U + 1*IMG;
  unsigned int* P2 = U + 2*IMG;    unsigned int* P3 = U + 3*IMG;
  unsigned int* P4 = U + 4*IMG;    unsigned int* P5 = U + 5*IMG;
  float* fcol = reinterpret_cast<float*>(P5);   // GJ arena (P5 dead until CP(W))
  float* brow = fcol + 32;

  // ---- muv_TE passthrough ----
  out[(size_t)B * 256 + batch * 16 + l] = mu_TE[batch * 32 + l];

  // ---- load + pack Lh/LhT/Hv/HvT; CP(Hv/HvT) kept in regs across GJ ----
  float tt[16];
  ldtile(chol_h, batch, p, q, tt);     storeRP(P0, p, q, tt);   // RP(Lh)
  ldtile(chol_h_TE, batch, p, q, tt);  storeRP(P1, p, q, tt);   // RP(LhT)
  unsigned int cphv[8], cphvT[8];
  ldtile(chol_hv, batch, p, q, tt);    storeRP(P2, p, q, tt);  packCP(tt, cphv);
  ldtile(chol_hv_TE, batch, p, q, tt); storeRP(P3, p, q, tt);  packCP(tt, cphvT);
  float pt[16];
  ldtile(prec_h, batch, p, q, pt);
  __syncthreads();

  float c[16];

  // ---- S = LhT@Lh^T + HvT@Hv^T (before GJ; doesn't need Pinv) ----
  zero16(c);
  mm1(P1, P0, p4, q4, c);             // A=RP(LhT), B-role of Lh^T = RP(Lh)
  mm1(P3, P2, p4, q4, c);             // A=RP(HvT), B-role of Hv^T = RP(Hv)
  __syncthreads();
  storeCP(P0, p, q, c);               // CP(S)   (RP(Lh) dead)

  // ---- Pinv = inv(prec_h): tile-layout Gauss-Jordan, f32; arena in P5 ----
  #pragma unroll
  for (int k = 0; k < 16; ++k) {
    const int kb = k >> 2, kc = k & 3, sel = (k & 1) * 16;
    if (q == kb) {
      *reinterpret_cast<float4*>(fcol + sel + p4) =
          make_float4(pt[0*4+kc], pt[1*4+kc], pt[2*4+kc], pt[3*4+kc]);
    }
    __syncthreads();
    if (p == kb) {
      const float rinv = 1.0f / fcol[sel + k];
      float sv[4];
      #pragma unroll
      for (int j = 0; j < 4; ++j) sv[j] = pt[kc*4+j] * rinv;
      if (q == kb) sv[kc] = rinv;
      *reinterpret_cast<float4*>(brow + sel + q4) = make_float4(sv[0], sv[1], sv[2], sv[3]);
    }
    __syncthreads();
    float4 f4 = *reinterpret_cast<const float4*>(fcol + sel + p4);
    float4 b4 = *reinterpret_cast<const float4*>(brow + sel + q4);
    const float fr[4] = {f4.x, f4.y, f4.z, f4.w};
    const float br[4] = {b4.x, b4.y, b4.z, b4.w};
    #pragma unroll
    for (int r = 0; r < 4; ++r) {
      const bool isPivRow = (p == kb) && (r == kc);
      #pragma unroll
      for (int j = 0; j < 4; ++j) {
        float base = pt[r*4+j];
        if (q == kb && j == kc) base = 0.f;
        const float nv = base - fr[r] * br[j];
        pt[r*4+j] = isPivRow ? br[j] : nv;
      }
    }
  }
  __syncthreads();                    // all GJ arena reads done
  storeRP(P4, p, q, pt);              // RP(Pinv) (= CP by symmetry)
  writeCPregs(P1, p, q, cphv);        // CP(Hv)   (RP(LhT) dead)
  writeCPregs(P2, p, q, cphvT);       // CP(HvT)  (RP(Hv) dead)
  __syncthreads();

  // ---- W1 = Pinv@S ----
  zero16(c);
  mm1(P4, P0, p4, q4, c);
  __syncthreads();
  storeRP(P3, p, q, c);               // RP(W1)   (RP(HvT) dead)
  __syncthreads();

  // ---- W = W1@Pinv ----
  zero16(c);
  mm1(P3, P4, p4, q4, c);
  __syncthreads();
  storeRP(P0, p, q, c);               // RP(W)    (CP(S) dead)
  storeCP(P5, p, q, c);               // CP(W)    (arena dead)
  __syncthreads();

  // ---- M1 = Pinv@Hv ----
  zero16(c);
  mm1(P4, P1, p4, q4, c);
  __syncthreads();
  storeCP(P3, p, q, c);               // CP(M1)   (RP(W1) dead)
  __syncthreads();

  // ---- U' = (W+W^T)@Hv ----
  zero16(c);
  mm2(P0, P5, P1, p4, q4, c);         // A = RP(W) + CP(W)
  __syncthreads();
  storeCP(P4, p, q, c);               // CP(U')   (Pinv dead)
  __syncthreads();

  // ---- Z = HvT^T@M1 ----
  zero16(c);
  mm1(P2, P3, p4, q4, c);             // A-role of HvT^T = CP(HvT)
  __syncthreads();
  storeRP(P0, p, q, c);               // RP(Z)    (RP(W) dead)
  storeCP(P5, p, q, c);               // CP(Z)    (CP(W) dead)
  __syncthreads();

  // ---- V2' = Hv^T@U' ----
  zero16(c);
  mm1(P1, P4, p4, q4, c);             // A-role of Hv^T = CP(Hv)
  __syncthreads();
  storeRP(P3, p, q, c);               // RP(V2')  (CP(M1) dead)
  float la[16];
  ldtile(chol_amat, batch, p, q, la);
  storeCP(P2, p, q, la);              // CP(La)   (CP(HvT) dead)
  storeRP(P1, p, q, la);              // RP(La)   (CP(Hv) dead)
  __syncthreads();

  // ---- cinv: forward substitution (lane l = column l), reads CP(La)=P2 ----
  float x[16];
  #pragma unroll
  for (int kp = 0; kp < 8; ++kp) {
    const int r0 = 2 * kp, r1 = r0 + 1;
    float a0 = 0.f, a1 = 0.f, h10 = 0.f;
    #pragma unroll
    for (int c2 = 0; c2 <= kp / 2; ++c2) {
      uint4 cv = *reinterpret_cast<const uint4*>(P2 + kp * PITCH + 4 * c2);
      const unsigned int cw[4] = {cv.x, cv.y, cv.z, cv.w};
      #pragma unroll
      for (int cc = 0; cc < 4; ++cc) {
        const int j = 4 * c2 + cc;
        h2 hp = __builtin_bit_cast(h2, cw[cc]);
        if (j < r0) a0 = fmaf(-(float)hp.x, x[j], a0);
        if (j < r0) a1 = fmaf(-(float)hp.y, x[j], a1);
        if (j == r0) h10 = (float)hp.y;
      }
    }
    x[r0] = ((l == r0) ? 1.f : 0.f) + a0;
    x[r1] = ((l == r1) ? 1.f : 0.f) + a1 - h10 * x[r0];
  }
  {
    float xp[16];
    #pragma unroll
    for (int j = 0; j < 16; ++j) xp[j] = dpp_swap1(x[j]);
    if ((l & 1) == 0) {                       // RP(cinv) -> P4 (CP(U') dead)
      unsigned int* dst = P4 + (l >> 1) * PITCH;
      #pragma unroll
      for (int c4 = 0; c4 < 4; ++c4) {
        uint4 w;
        w.x = pkf(x[4*c4+0], xp[4*c4+0]); w.y = pkf(x[4*c4+1], xp[4*c4+1]);
        w.z = pkf(x[4*c4+2], xp[4*c4+2]); w.w = pkf(x[4*c4+3], xp[4*c4+3]);
        *reinterpret_cast<uint4*>(dst + 4*c4) = w;
      }
    }
  }
  __syncthreads();

  // ---- Y = (V2' - Z - Z^T) @ cinv^T ----
  zero16(c);
  mm3(P3, P0, P5, P4, p4, q4, c);     // B-role of cinv^T = RP(cinv)
  __syncthreads();
  storeCP(P0, p, q, c);               // CP(Y)    (RP(Z) dead)
  __syncthreads();

  // ---- arg = cinv@Y, phi mask ----
  zero16(c);
  mm1(P4, P0, p4, q4, c);             // A-role of cinv = RP(cinv)
  #pragma unroll
  for (int r = 0; r < 4; ++r)
    #pragma unroll
    for (int j = 0; j < 4; ++j) {
      const int gi = p4 + r, gj = q4 + j;
      c[r*4+j] = (gi > gj) ? c[r*4+j] : ((gi == gj) ? 0.5f * c[r*4+j] : 0.f);
    }
  __syncthreads();
  storeCP(P5, p, q, c);               // CP(arg)  (CP(Z) dead)
  __syncthreads();

  // ---- camTE = La @ masked ----
  zero16(c);
  mm1(P1, P5, p4, q4, c);             // A=RP(La), B=CP(arg)
  __syncthreads();
  storeCP(P3, p, q, c);               // CP(cam)  (RP(V2') dead)
  ldtile(chol_v_TE, batch, p, q, tt); storeRP(P0, p, q, tt);   // RP(LvT) (CP(Y) dead)
  float tv[16];
  ldtile(chol_v, batch, p, q, tv);    storeRP(P4, p, q, tv);   // RP(Lv)  (RP(cinv) dead)
  __syncthreads();

  // ---- out = LvT@La + Lv@camTE ----
  zero16(c);
  mm1(P0, P2, p4, q4, c);             // B=CP(La) still live
  mm1(P4, P3, p4, q4, c);
  {
    float* base = out + batch * 256 + p * 64 + q * 4;
    #pragma unroll
    for (int r = 0; r < 4; ++r)
      *reinterpret_cast<float4*>(base + r * 16) =
          make_float4(c[r*4+0], c[r*4+1], c[r*4+2], c[r*4+3]);
  }
}

extern "C" void kernel_launch(void* const* d_in, const int* in_sizes, int n_in,
                              void* d_out, int out_size, void* d_ws, size_t ws_size,
                              hipStream_t stream) {
  const float* mu_TE      = (const float*)d_in[0];
  const float* prec_h     = (const float*)d_in[1];
  const float* chol_v     = (const float*)d_in[2];
  const float* chol_h     = (const float*)d_in[3];
  const float* chol_hv    = (const float*)d_in[4];
  const float* chol_v_TE  = (const float*)d_in[5];
  const float* chol_h_TE  = (const float*)d_in[6];
  const float* chol_hv_TE = (const float*)d_in[7];
  const float* chol_amat  = (const float*)d_in[8];
  float* out = (float*)d_out;

  const int B = in_sizes[0] / 32;     // mu_TE is (B, 32)
  gauss_te_pk6<<<B / 4, 64, 0, stream>>>(mu_TE, prec_h, chol_v, chol_h, chol_hv,
                                         chol_v_TE, chol_h_TE, chol_hv_TE,
                                         chol_amat, out, B);
}

// Round 6
// 131.948 us; speedup vs baseline: 5.4876x; 1.1129x over previous
//
#include <hip/hip_runtime.h>

// ConvertParamsTEtoParams0TEGaussLayer — tile4 + packed-f16 fdot2, 5-slot LDS,
// barrier-free (single-wave blocks + in-order LDS pipe).
// 64-thread blocks = 1 wave = 4 batches (16 lanes each). Lane (p,q) owns the
// 4x4 tile C[4p..4p+3][4q..4q+3]. Operands in LDS as f16 pairs packed along K.
//
//   RP(X)[kp][i] = pack(X[i][2kp], X[i][2kp+1])  == A-role of X, B-role of X^T
//   CP(X)[kp][j] = pack(X[2kp][j], X[2kp+1][j])  == B-role of X, A-role of X^T
//
// PITCH=20 (store-conflict-free, round-4 verified); 5 slots x 160 + 8 skew
// = 808 u32/batch -> 12928 B/block -> 12 blocks/CU.
// Z^T obtained by 16 in-wave lane shuffles (tile transpose), so amatTE =
// V2' - Z - Z^T is formed in f32 registers: no Z images needed.
//
// Block = 1 wave and same-wave LDS ops execute in order, so __syncthreads()
// is replaced by __builtin_amdgcn_wave_barrier() (compiler fence, 0 instr).
//
// Slot lifetime schedule:
//   P0: RP(Lh) -> RP(Pinv) -> CP(M1) -> RP(amatTE) -> CP(arg) -> RP(LvT)
//   P1: RP(LhT) -> [GJ arena] -> RP(W1) -> CP(W) -> CP(La)
//   P2: RP(Hv) -> CP(Hv) -> RP(cinv) -> RP(Lv)
//   P3: RP(HvT) -> CP(HvT) -> RP(La)
//   P4: CP(S) -> RP(W) -> CP(U') -> CP(Y) -> CP(cam)

typedef _Float16 h2 __attribute__((ext_vector_type(2)));

constexpr int PITCH = 20;               // u32 per kp-row
constexpr int IMG   = 8 * PITCH;        // 160 u32 per packed image
constexpr int NSLOT = 5;
constexpr int BSTR  = NSLOT * IMG + 8;  // 808 u32; 808 % 32 == 8 -> bank skew

#define WBAR() __builtin_amdgcn_wave_barrier()

__device__ __forceinline__ unsigned int pkf(float a, float b) {
  return __builtin_bit_cast(unsigned int, __builtin_amdgcn_cvt_pkrtz(a, b));
}
__device__ __forceinline__ unsigned int h2add(unsigned int a, unsigned int b) {
  return __builtin_bit_cast(unsigned int,
      (h2)(__builtin_bit_cast(h2, a) + __builtin_bit_cast(h2, b)));
}
__device__ __forceinline__ float fd2(unsigned int a, unsigned int b, float c) {
#if __has_builtin(__builtin_amdgcn_fdot2)
  return __builtin_amdgcn_fdot2(__builtin_bit_cast(h2, a), __builtin_bit_cast(h2, b), c, false);
#else
  h2 ha = __builtin_bit_cast(h2, a), hb = __builtin_bit_cast(h2, b);
  return c + (float)ha.x * (float)hb.x + (float)ha.y * (float)hb.y;
#endif
}
__device__ __forceinline__ float dpp_swap1(float v) {  // lane c <-> c^1 (quad_perm 1,0,3,2)
  return __int_as_float(__builtin_amdgcn_update_dpp(
      0, __float_as_int(v), 0xB1, 0xF, 0xF, false));
}

__device__ __forceinline__ void zero16(float (&v)[16]) {
  #pragma unroll
  for (int j = 0; j < 16; ++j) v[j] = 0.f;
}

__device__ __forceinline__ void ldtile(const float* __restrict__ g, size_t batch,
                                       int p, int q, float (&c)[16]) {
  const float* base = g + batch * 256 + p * 64 + q * 4;
  #pragma unroll
  for (int r = 0; r < 4; ++r) {
    float4 v = *reinterpret_cast<const float4*>(base + r * 16);
    c[r*4+0] = v.x; c[r*4+1] = v.y; c[r*4+2] = v.z; c[r*4+3] = v.w;
  }
}

__device__ __forceinline__ void storeRP(unsigned int* img, int p, int q, const float (&c)[16]) {
  #pragma unroll
  for (int r = 0; r < 4; ++r) {
    img[(2*q  ) * PITCH + 4*p + r] = pkf(c[r*4+0], c[r*4+1]);
    img[(2*q+1) * PITCH + 4*p + r] = pkf(c[r*4+2], c[r*4+3]);
  }
}
__device__ __forceinline__ void packCP(const float (&c)[16], unsigned int (&w)[8]) {
  w[0] = pkf(c[0],  c[4]);  w[1] = pkf(c[1],  c[5]);
  w[2] = pkf(c[2],  c[6]);  w[3] = pkf(c[3],  c[7]);
  w[4] = pkf(c[8],  c[12]); w[5] = pkf(c[9],  c[13]);
  w[6] = pkf(c[10], c[14]); w[7] = pkf(c[11], c[15]);
}
__device__ __forceinline__ void writeCPregs(unsigned int* img, int p, int q,
                                            const unsigned int (&w)[8]) {
  *reinterpret_cast<uint4*>(img + (2*p  ) * PITCH + 4*q) = make_uint4(w[0], w[1], w[2], w[3]);
  *reinterpret_cast<uint4*>(img + (2*p+1) * PITCH + 4*q) = make_uint4(w[4], w[5], w[6], w[7]);
}
__device__ __forceinline__ void storeCP(unsigned int* img, int p, int q, const float (&c)[16]) {
  unsigned int w[8];
  packCP(c, w);
  writeCPregs(img, p, q, w);
}

// c[r*4+j] += sum_k A[4p+r][k] * B[k][4q+j]; A RP-style, B CP-style.
__device__ __forceinline__ void mm1(const unsigned int* __restrict__ A,
                                    const unsigned int* __restrict__ Bm,
                                    int p4, int q4, float (&c)[16]) {
  #pragma unroll
  for (int kp = 0; kp < 8; ++kp) {
    uint4 av = *reinterpret_cast<const uint4*>(A  + kp * PITCH + p4);
    uint4 bv = *reinterpret_cast<const uint4*>(Bm + kp * PITCH + q4);
    const unsigned int ar[4] = {av.x, av.y, av.z, av.w};
    const unsigned int br[4] = {bv.x, bv.y, bv.z, bv.w};
    #pragma unroll
    for (int r = 0; r < 4; ++r)
      #pragma unroll
      for (int j = 0; j < 4; ++j)
        c[r*4+j] = fd2(ar[r], br[j], c[r*4+j]);
  }
}
// A = A0 + A1 (packed f16 add on the fly)
__device__ __forceinline__ void mm2(const unsigned int* __restrict__ A0,
                                    const unsigned int* __restrict__ A1,
                                    const unsigned int* __restrict__ Bm,
                                    int p4, int q4, float (&c)[16]) {
  #pragma unroll
  for (int kp = 0; kp < 8; ++kp) {
    uint4 a0 = *reinterpret_cast<const uint4*>(A0 + kp * PITCH + p4);
    uint4 a1 = *reinterpret_cast<const uint4*>(A1 + kp * PITCH + p4);
    uint4 bv = *reinterpret_cast<const uint4*>(Bm + kp * PITCH + q4);
    const unsigned int ar[4] = {h2add(a0.x, a1.x), h2add(a0.y, a1.y),
                                h2add(a0.z, a1.z), h2add(a0.w, a1.w)};
    const unsigned int br[4] = {bv.x, bv.y, bv.z, bv.w};
    #pragma unroll
    for (int r = 0; r < 4; ++r)
      #pragma unroll
      for (int j = 0; j < 4; ++j)
        c[r*4+j] = fd2(ar[r], br[j], c[r*4+j]);
  }
}

__global__ __launch_bounds__(64, 3) void gauss_te_pk5(
    const float* __restrict__ mu_TE,
    const float* __restrict__ prec_h,
    const float* __restrict__ chol_v,
    const float* __restrict__ chol_h,
    const float* __restrict__ chol_hv,
    const float* __restrict__ chol_v_TE,
    const float* __restrict__ chol_h_TE,
    const float* __restrict__ chol_hv_TE,
    const float* __restrict__ chol_amat,
    float* __restrict__ out, int B)
{
  __shared__ __align__(16) unsigned int slab[4 * BSTR];
  const int t = threadIdx.x;
  const int g = t >> 4;
  const int l = t & 15;
  const int p = l >> 2, q = l & 3;
  const int p4 = 4 * p, q4 = 4 * q;
  const size_t batch = (size_t)blockIdx.x * 4 + g;

  unsigned int* U = slab + g * BSTR;
  unsigned int* P0 = U;            unsigned int* P1 = U + 1*IMG;
  unsigned int* P2 = U + 2*IMG;    unsigned int* P3 = U + 3*IMG;
  unsigned int* P4 = U + 4*IMG;
  float* fcol = reinterpret_cast<float*>(P1);   // GJ arena (P1 dead during GJ)
  float* brow = fcol + 32;

  // ---- muv_TE passthrough ----
  out[(size_t)B * 256 + batch * 16 + l] = mu_TE[batch * 32 + l];

  // ---- load + pack inputs; La prefetched for later ----
  float tt[16];
  ldtile(chol_h, batch, p, q, tt);     storeRP(P0, p, q, tt);   // RP(Lh)
  ldtile(chol_h_TE, batch, p, q, tt);  storeRP(P1, p, q, tt);   // RP(LhT)
  unsigned int cphv[8], cphvT[8];
  ldtile(chol_hv, batch, p, q, tt);    storeRP(P2, p, q, tt);  packCP(tt, cphv);
  ldtile(chol_hv_TE, batch, p, q, tt); storeRP(P3, p, q, tt);  packCP(tt, cphvT);
  float pt[16];
  ldtile(prec_h, batch, p, q, pt);
  float la[16];
  ldtile(chol_amat, batch, p, q, la);   // prefetch (used after GJ)
  WBAR();

  float c[16];

  // ---- S = LhT@Lh^T + HvT@Hv^T ----
  zero16(c);
  mm1(P1, P0, p4, q4, c);
  mm1(P3, P2, p4, q4, c);
  storeCP(P4, c != nullptr ? p : p, q, c);   // CP(S)  (P4 fresh)
  WBAR();
  writeCPregs(P2, p, q, cphv);        // CP(Hv)   (RP(Hv) dead)
  writeCPregs(P3, p, q, cphvT);       // CP(HvT)  (RP(HvT) dead)
  WBAR();

  // ---- Pinv = inv(prec_h): tile-layout Gauss-Jordan, f32; arena in P1 ----
  #pragma unroll
  for (int k = 0; k < 16; ++k) {
    const int kb = k >> 2, kc = k & 3, sel = (k & 1) * 16;
    if (q == kb) {
      *reinterpret_cast<float4*>(fcol + sel + p4) =
          make_float4(pt[0*4+kc], pt[1*4+kc], pt[2*4+kc], pt[3*4+kc]);
    }
    WBAR();
    if (p == kb) {
      const float rinv = 1.0f / fcol[sel + k];
      float sv[4];
      #pragma unroll
      for (int j = 0; j < 4; ++j) sv[j] = pt[kc*4+j] * rinv;
      if (q == kb) sv[kc] = rinv;
      *reinterpret_cast<float4*>(brow + sel + q4) = make_float4(sv[0], sv[1], sv[2], sv[3]);
    }
    WBAR();
    float4 f4 = *reinterpret_cast<const float4*>(fcol + sel + p4);
    float4 b4 = *reinterpret_cast<const float4*>(brow + sel + q4);
    const float fr[4] = {f4.x, f4.y, f4.z, f4.w};
    const float br[4] = {b4.x, b4.y, b4.z, b4.w};
    #pragma unroll
    for (int r = 0; r < 4; ++r) {
      const bool isPivRow = (p == kb) && (r == kc);
      #pragma unroll
      for (int j = 0; j < 4; ++j) {
        float base = pt[r*4+j];
        if (q == kb && j == kc) base = 0.f;
        const float nv = base - fr[r] * br[j];
        pt[r*4+j] = isPivRow ? br[j] : nv;
      }
    }
  }
  WBAR();
  storeRP(P0, p, q, pt);              // RP(Pinv) = CP(Pinv) (symmetric)
  WBAR();

  // ---- W1 = Pinv@S ----
  zero16(c);
  mm1(P0, P4, p4, q4, c);
  WBAR();
  storeRP(P1, p, q, c);               // RP(W1)  (arena dead)
  WBAR();

  // ---- W = W1@Pinv ----
  zero16(c);
  mm1(P1, P0, p4, q4, c);
  WBAR();
  storeRP(P4, p, q, c);               // RP(W)   (CP(S) dead)
  storeCP(P1, p, q, c);               // CP(W)   (W1 dead)
  WBAR();

  // ---- M1 = Pinv@Hv ----
  zero16(c);
  mm1(P0, P2, p4, q4, c);
  WBAR();
  storeCP(P0, p, q, c);               // CP(M1)  (Pinv dead)
  WBAR();

  // ---- U' = (W+W^T)@Hv ----
  zero16(c);
  mm2(P4, P1, P2, p4, q4, c);
  WBAR();
  storeCP(P4, p, q, c);               // CP(U')  (RP(W) dead)
  WBAR();

  // ---- Z = HvT^T@M1 ; zsum = Z + Z^T (lane-shuffle transpose) ----
  zero16(c);
  mm1(P3, P0, p4, q4, c);             // A-role of HvT^T = CP(HvT)
  const int srcT = (t & 48) | ((t & 3) << 2) | ((t >> 2) & 3);  // lane (q,p)
  float zsum[16];
  #pragma unroll
  for (int r = 0; r < 4; ++r)
    #pragma unroll
    for (int j = 0; j < 4; ++j)
      zsum[r*4+j] = c[r*4+j] + __shfl(c[j*4+r], srcT, 64);
  WBAR();

  // ---- V2' = Hv^T@U' ; amatTE = V2' - Z - Z^T (f32 regs) ----
  zero16(c);
  mm1(P2, P4, p4, q4, c);             // A-role of Hv^T = CP(Hv)
  #pragma unroll
  for (int j = 0; j < 16; ++j) c[j] -= zsum[j];
  WBAR();
  storeRP(P0, p, q, c);               // RP(amatTE)  (CP(M1) dead)
  storeCP(P1, p, q, la);              // CP(La)      (CP(W) dead)
  storeRP(P3, p, q, la);              // RP(La)      (CP(HvT) dead)
  WBAR();

  // ---- cinv: forward substitution (lane l = column l), reads CP(La)=P1 ----
  float x[16];
  #pragma unroll
  for (int kp = 0; kp < 8; ++kp) {
    const int r0 = 2 * kp, r1 = r0 + 1;
    float a0 = 0.f, a1 = 0.f, h10 = 0.f;
    #pragma unroll
    for (int c2 = 0; c2 <= kp / 2; ++c2) {
      uint4 cv = *reinterpret_cast<const uint4*>(P1 + kp * PITCH + 4 * c2);
      const unsigned int cw[4] = {cv.x, cv.y, cv.z, cv.w};
      #pragma unroll
      for (int cc = 0; cc < 4; ++cc) {
        const int j = 4 * c2 + cc;
        h2 hp = __builtin_bit_cast(h2, cw[cc]);
        if (j < r0) a0 = fmaf(-(float)hp.x, x[j], a0);
        if (j < r0) a1 = fmaf(-(float)hp.y, x[j], a1);
        if (j == r0) h10 = (float)hp.y;
      }
    }
    x[r0] = ((l == r0) ? 1.f : 0.f) + a0;
    x[r1] = ((l == r1) ? 1.f : 0.f) + a1 - h10 * x[r0];
  }
  {
    float xp[16];
    #pragma unroll
    for (int j = 0; j < 16; ++j) xp[j] = dpp_swap1(x[j]);
    if ((l & 1) == 0) {                       // RP(cinv) -> P2 (CP(Hv) dead)
      unsigned int* dst = P2 + (l >> 1) * PITCH;
      #pragma unroll
      for (int c4 = 0; c4 < 4; ++c4) {
        uint4 w;
        w.x = pkf(x[4*c4+0], xp[4*c4+0]); w.y = pkf(x[4*c4+1], xp[4*c4+1]);
        w.z = pkf(x[4*c4+2], xp[4*c4+2]); w.w = pkf(x[4*c4+3], xp[4*c4+3]);
        *reinterpret_cast<uint4*>(dst + 4*c4) = w;
      }
    }
  }
  WBAR();

  // ---- prefetch Lv/LvT (consumed 3 passes later) ----
  float lvt[16], lv[16];
  ldtile(chol_v_TE, batch, p, q, lvt);
  ldtile(chol_v, batch, p, q, lv);

  // ---- Y = amatTE @ cinv^T ----
  zero16(c);
  mm1(P0, P2, p4, q4, c);             // B-role of cinv^T = RP(cinv)
  WBAR();
  storeCP(P4, p, q, c);               // CP(Y)   (CP(U') dead)
  WBAR();

  // ---- arg = cinv@Y, phi mask ----
  zero16(c);
  mm1(P2, P4, p4, q4, c);             // A-role of cinv = RP(cinv)
  #pragma unroll
  for (int r = 0; r < 4; ++r)
    #pragma unroll
    for (int j = 0; j < 4; ++j) {
      const int gi = p4 + r, gj = q4 + j;
      c[r*4+j] = (gi > gj) ? c[r*4+j] : ((gi == gj) ? 0.5f * c[r*4+j] : 0.f);
    }
  WBAR();
  storeCP(P0, p, q, c);               // CP(arg) (amatTE dead)
  WBAR();

  // ---- camTE = La @ masked ----
  zero16(c);
  mm1(P3, P0, p4, q4, c);             // A=RP(La), B=CP(arg)
  WBAR();
  storeCP(P4, p, q, c);               // CP(cam) (Y dead)
  storeRP(P0, p, q, lvt);             // RP(LvT) (arg dead)
  storeRP(P2, p, q, lv);              // RP(Lv)  (cinv dead)
  WBAR();

  // ---- out = LvT@La + Lv@camTE ----
  zero16(c);
  mm1(P0, P1, p4, q4, c);             // B=CP(La) still live
  mm1(P2, P4, p4, q4, c);
  {
    float* base = out + batch * 256 + p * 64 + q * 4;
    #pragma unroll
    for (int r = 0; r < 4; ++r)
      *reinterpret_cast<float4*>(base + r * 16) =
          make_float4(c[r*4+0], c[r*4+1], c[r*4+2], c[r*4+3]);
  }
}

extern "C" void kernel_launch(void* const* d_in, const int* in_sizes, int n_in,
                              void* d_out, int out_size, void* d_ws, size_t ws_size,
                              hipStream_t stream) {
  const float* mu_TE      = (const float*)d_in[0];
  const float* prec_h     = (const float*)d_in[1];
  const float* chol_v     = (const float*)d_in[2];
  const float* chol_h     = (const float*)d_in[3];
  const float* chol_hv    = (const float*)d_in[4];
  const float* chol_v_TE  = (const float*)d_in[5];
  const float* chol_h_TE  = (const float*)d_in[6];
  const float* chol_hv_TE = (const float*)d_in[7];
  const float* chol_amat  = (const float*)d_in[8];
  float* out = (float*)d_out;

  const int B = in_sizes[0] / 32;     // mu_TE is (B, 32)
  gauss_te_pk5<<<B / 4, 64, 0, stream>>>(mu_TE, prec_h, chol_v, chol_h, chol_hv,
                                         chol_v_TE, chol_h_TE, chol_hv_TE,
                                         chol_amat, out, B);
}

// Round 7
// 126.584 us; speedup vs baseline: 5.7201x; 1.0424x over previous
//
#include <hip/hip_runtime.h>

// ConvertParamsTEtoParams0TEGaussLayer — MFMA version.
// 64-thread blocks = 1 wave = 4 batches. Tile path (16-lane groups) does the
// f32 Gauss-Jordan inverse of prec_h and the unit-lower forward substitution
// (both validated in prior rounds); all 13 matrix products run on the matrix
// pipe via v_mfma_f32_16x16x16_f16 (f16 operands, f32 accumulate).
//
// Fragment layouts (verified family, m89): for 16x16x16 f16, lane l=(h=l>>4,c=l&15):
//   A-frag reg i = A[c][4h+i]      B-frag reg i = B[4h+i][c]
//   D     reg j = D[4h+j][c]  ==  B-frag layout  => D->B chaining is 2 cvt_pkrtz.
//   A-frag(X^T) == B-frag(X) (identical registers).
// Intermediates needed in A position (W1, W, Z, T1) round-trip through a
// per-batch LDS scratch slot: 2 ds_write_b32 (CP layout) + 1 ds_read_b128+2 perm.
//
// LDS per batch: 4 slots (CP(Pinv), CP(La), RP(cinv), scratch/GJ-arena)
// = 648 u32 -> 10368 B/block -> 15 blocks/CU.

typedef _Float16 h2    __attribute__((ext_vector_type(2)));
typedef _Float16 f16x4 __attribute__((ext_vector_type(4)));
typedef float    f32x4 __attribute__((ext_vector_type(4)));

constexpr int PITCH = 20;             // u32 per kp-row
constexpr int IMG   = 8 * PITCH;      // 160 u32 per packed image
constexpr int BSTR  = 4 * IMG + 8;    // 648 u32; %32==8 -> bank skew per batch

#define WBAR() __builtin_amdgcn_wave_barrier()

__device__ __forceinline__ unsigned int pkf(float a, float b) {
  return __builtin_bit_cast(unsigned int, __builtin_amdgcn_cvt_pkrtz(a, b));
}
__device__ __forceinline__ f16x4 mkf16x4(unsigned int lo, unsigned int hi) {
  union { unsigned int u[2]; f16x4 v; } cv; cv.u[0] = lo; cv.u[1] = hi; return cv.v;
}
__device__ __forceinline__ f16x4 cvt4(f32x4 d) {
  return mkf16x4(pkf(d[0], d[1]), pkf(d[2], d[3]));
}
__device__ __forceinline__ f16x4 cvt4f(float a, float b, float c, float d) {
  return mkf16x4(pkf(a, b), pkf(c, d));
}
__device__ __forceinline__ float dpp_swap1(float v) {  // lane c <-> c^1
  return __int_as_float(__builtin_amdgcn_update_dpp(
      0, __float_as_int(v), 0xB1, 0xF, 0xF, false));
}
__device__ __forceinline__ f32x4 MF(f16x4 a, f16x4 b, f32x4 c) {
  return __builtin_amdgcn_mfma_f32_16x16x16f16(a, b, c, 0, 0, 0);
}

// ---- tile-phase helpers (validated rounds 4-6) ----
__device__ __forceinline__ void ldtile(const float* __restrict__ g, size_t batch,
                                       int p, int q, float (&c)[16]) {
  const float* base = g + batch * 256 + p * 64 + q * 4;
  #pragma unroll
  for (int r = 0; r < 4; ++r) {
    float4 v = *reinterpret_cast<const float4*>(base + r * 16);
    c[r*4+0] = v.x; c[r*4+1] = v.y; c[r*4+2] = v.z; c[r*4+3] = v.w;
  }
}
__device__ __forceinline__ void storeRP(unsigned int* img, int p, int q, const float (&c)[16]) {
  #pragma unroll
  for (int r = 0; r < 4; ++r) {
    img[(2*q  ) * PITCH + 4*p + r] = pkf(c[r*4+0], c[r*4+1]);
    img[(2*q+1) * PITCH + 4*p + r] = pkf(c[r*4+2], c[r*4+3]);
  }
}
__device__ __forceinline__ void storeCPt(unsigned int* img, int p, int q, const float (&c)[16]) {
  uint4 w0, w1;
  w0.x = pkf(c[0],  c[4]);  w0.y = pkf(c[1],  c[5]);
  w0.z = pkf(c[2],  c[6]);  w0.w = pkf(c[3],  c[7]);
  w1.x = pkf(c[8],  c[12]); w1.y = pkf(c[9],  c[13]);
  w1.z = pkf(c[10], c[14]); w1.w = pkf(c[11], c[15]);
  *reinterpret_cast<uint4*>(img + (2*p  ) * PITCH + 4*q) = w0;
  *reinterpret_cast<uint4*>(img + (2*p+1) * PITCH + 4*q) = w1;
}

// ---- MFMA fragment helpers ----
// A-frag from global (row pattern): X[r][4h..4h+3]; also = B-frag(X^T).
__device__ __forceinline__ f16x4 ldA(const float* __restrict__ X, int r, int h) {
  float4 v = *reinterpret_cast<const float4*>(X + r * 16 + 4 * h);
  return cvt4f(v.x, v.y, v.z, v.w);
}
// B-frag from global (column pattern): X[4h+i][c]; also = A-frag(X^T).
__device__ __forceinline__ f16x4 ldBcol(const float* __restrict__ X, int h, int c) {
  const float* b = X + 4 * h * 16 + c;
  return cvt4f(b[0], b[16], b[32], b[48]);
}
// B-frag from CP image: 2x ds_read_b32.
__device__ __forceinline__ f16x4 ldsB(const unsigned int* img, int h, int c) {
  return mkf16x4(img[(2*h) * PITCH + c], img[(2*h+1) * PITCH + c]);
}
// A-frag from CP image: 1x ds_read_b128 + 2x v_perm (select f16 half by r&1).
__device__ __forceinline__ f16x4 ldsA(const unsigned int* img, int r, int h) {
  uint4 u = *reinterpret_cast<const uint4*>(img + (r >> 1) * PITCH + 4 * h);
  unsigned int sel = 0x05040100u + (unsigned)(r & 1) * 0x02020202u;
  return mkf16x4(__builtin_amdgcn_perm(u.y, u.x, sel),
                 __builtin_amdgcn_perm(u.w, u.z, sel));
}
// D (f32x4) -> CP image: 2 pkrtz + 2 ds_write_b32.
__device__ __forceinline__ void stCP(unsigned int* img, int h, int c, f32x4 d) {
  img[(2*h)   * PITCH + c] = pkf(d[0], d[1]);
  img[(2*h+1) * PITCH + c] = pkf(d[2], d[3]);
}

__global__ __launch_bounds__(64, 4) void gauss_te_mf(
    const float* __restrict__ mu_TE,
    const float* __restrict__ prec_h,
    const float* __restrict__ chol_v,
    const float* __restrict__ chol_h,
    const float* __restrict__ chol_hv,
    const float* __restrict__ chol_v_TE,
    const float* __restrict__ chol_h_TE,
    const float* __restrict__ chol_hv_TE,
    const float* __restrict__ chol_amat,
    float* __restrict__ out, int B)
{
  __shared__ __align__(16) unsigned int slab[4 * BSTR];
  const int t = threadIdx.x;
  const int g = t >> 4;                 // group / h-role
  const int l = t & 15;                 // lane-in-group / c-role
  const int p = l >> 2, q = l & 3;      // tile coords (GJ/subst phase)
  const size_t batch0 = (size_t)blockIdx.x * 4;
  const size_t tb = batch0 + g;

  unsigned int* Ut  = slab + g * BSTR;
  unsigned int* Q0t = Ut;               // CP(Pinv)
  unsigned int* Q1t = Ut + IMG;         // CP(La)
  unsigned int* Q2t = Ut + 2 * IMG;     // RP(cinv)
  unsigned int* Q3t = Ut + 3 * IMG;     // GJ arena, later RT scratch
  float* fcol = reinterpret_cast<float*>(Q3t);
  float* brow = fcol + 32;

  // ---- muv_TE passthrough ----
  out[(size_t)B * 256 + tb * 16 + l] = mu_TE[tb * 32 + l];

  // ---- prefetch S-inputs for all 4 batches into f16 fragments ----
  f16x4 pfA0[4], pfB0[4], pfA1[4], pfB1[4];
  #pragma unroll
  for (int b = 0; b < 4; ++b) {
    const size_t off = (batch0 + b) * 256;
    pfA0[b] = ldA(chol_h_TE  + off, l, g);  // A-frag(LhT)
    pfB0[b] = ldA(chol_h     + off, l, g);  // B-frag(Lh^T)
    pfA1[b] = ldA(chol_hv_TE + off, l, g);  // A-frag(HvT)
    pfB1[b] = ldA(chol_hv    + off, l, g);  // B-frag(Hv^T)
  }

  // ---- tile phase: stage CP(La), GJ inverse of prec_h ----
  float la[16];
  ldtile(chol_amat, tb, p, q, la);
  storeCPt(Q1t, p, q, la);
  float pt[16];
  ldtile(prec_h, tb, p, q, pt);
  WBAR();

  #pragma unroll
  for (int k = 0; k < 16; ++k) {
    const int kb = k >> 2, kc = k & 3, sel = (k & 1) * 16;
    if (q == kb) {
      *reinterpret_cast<float4*>(fcol + sel + 4 * p) =
          make_float4(pt[0*4+kc], pt[1*4+kc], pt[2*4+kc], pt[3*4+kc]);
    }
    WBAR();
    if (p == kb) {
      const float rinv = 1.0f / fcol[sel + k];
      float sv[4];
      #pragma unroll
      for (int j = 0; j < 4; ++j) sv[j] = pt[kc*4+j] * rinv;
      if (q == kb) sv[kc] = rinv;
      *reinterpret_cast<float4*>(brow + sel + 4 * q) = make_float4(sv[0], sv[1], sv[2], sv[3]);
    }
    WBAR();
    float4 f4 = *reinterpret_cast<const float4*>(fcol + sel + 4 * p);
    float4 b4 = *reinterpret_cast<const float4*>(brow + sel + 4 * q);
    const float fr[4] = {f4.x, f4.y, f4.z, f4.w};
    const float br[4] = {b4.x, b4.y, b4.z, b4.w};
    #pragma unroll
    for (int r = 0; r < 4; ++r) {
      const bool isPivRow = (p == kb) && (r == kc);
      #pragma unroll
      for (int j = 0; j < 4; ++j) {
        float base = pt[r*4+j];
        if (q == kb && j == kc) base = 0.f;
        const float nv = base - fr[r] * br[j];
        pt[r*4+j] = isPivRow ? br[j] : nv;
      }
    }
  }
  WBAR();
  storeRP(Q0t, p, q, pt);               // RP(Pinv) == CP(Pinv) (symmetric)
  WBAR();

  // ---- cinv: forward substitution (lane l = column l), reads CP(La) ----
  float x[16];
  #pragma unroll
  for (int kp = 0; kp < 8; ++kp) {
    const int r0 = 2 * kp, r1 = r0 + 1;
    float a0 = 0.f, a1 = 0.f, h10 = 0.f;
    #pragma unroll
    for (int c2 = 0; c2 <= kp / 2; ++c2) {
      uint4 cv = *reinterpret_cast<const uint4*>(Q1t + kp * PITCH + 4 * c2);
      const unsigned int cw[4] = {cv.x, cv.y, cv.z, cv.w};
      #pragma unroll
      for (int cc = 0; cc < 4; ++cc) {
        const int j = 4 * c2 + cc;
        h2 hp = __builtin_bit_cast(h2, cw[cc]);
        if (j < r0) a0 = fmaf(-(float)hp.x, x[j], a0);
        if (j < r0) a1 = fmaf(-(float)hp.y, x[j], a1);
        if (j == r0) h10 = (float)hp.y;
      }
    }
    x[r0] = ((l == r0) ? 1.f : 0.f) + a0;
    x[r1] = ((l == r1) ? 1.f : 0.f) + a1 - h10 * x[r0];
  }
  {
    float xp[16];
    #pragma unroll
    for (int j = 0; j < 16; ++j) xp[j] = dpp_swap1(x[j]);
    if ((l & 1) == 0) {                 // RP(cinv) -> Q2
      unsigned int* dst = Q2t + (l >> 1) * PITCH;
      #pragma unroll
      for (int c4 = 0; c4 < 4; ++c4) {
        uint4 w;
        w.x = pkf(x[4*c4+0], xp[4*c4+0]); w.y = pkf(x[4*c4+1], xp[4*c4+1]);
        w.z = pkf(x[4*c4+2], xp[4*c4+2]); w.w = pkf(x[4*c4+3], xp[4*c4+3]);
        *reinterpret_cast<uint4*>(dst + 4*c4) = w;
      }
    }
  }
  WBAR();

  // ---- MFMA phase: 2 batch-chains interleaved per pair ----
  const f32x4 zz = {0.f, 0.f, 0.f, 0.f};
  #pragma unroll
  for (int gb = 0; gb < 4; gb += 2) {
    const unsigned int* Q0[2] = { slab + (gb+0)*BSTR, slab + (gb+1)*BSTR };
    const unsigned int* Q1[2] = { Q0[0] + IMG,        Q0[1] + IMG };
    const unsigned int* Q2[2] = { Q0[0] + 2*IMG,      Q0[1] + 2*IMG };
    unsigned int*       Q3[2] = { slab + (gb+0)*BSTR + 3*IMG,
                                  slab + (gb+1)*BSTR + 3*IMG };
    const size_t off[2] = { (batch0 + gb + 0) * 256, (batch0 + gb + 1) * 256 };

    f16x4 pinvA[2], pinvB[2], hvB[2], cA[2], sumA[2];
    f32x4 W[2], M1[2], Up[2], Zt[2], V2[2];

    #pragma unroll
    for (int u = 0; u < 2; ++u) {
      f32x4 S = MF(pfA0[gb+u], pfB0[gb+u], zz);     // LhT @ Lh^T
      S = MF(pfA1[gb+u], pfB1[gb+u], S);            // + HvT @ Hv^T
      pinvA[u] = ldsA(Q0[u], l, g);
      pinvB[u] = ldsB(Q0[u], g, l);
      f32x4 W1 = MF(pinvA[u], cvt4(S), zz);         // W1 = Pinv@S
      stCP(Q3[u], g, l, W1);
    }
    WBAR();
    #pragma unroll
    for (int u = 0; u < 2; ++u) {
      f16x4 w1A = ldsA(Q3[u], l, g);
      W[u] = MF(w1A, pinvB[u], zz);                 // W = W1@Pinv
    }
    #pragma unroll
    for (int u = 0; u < 2; ++u) stCP(Q3[u], g, l, W[u]);
    WBAR();
    #pragma unroll
    for (int u = 0; u < 2; ++u) {
      f16x4 wA = ldsA(Q3[u], l, g);                 // A-frag(W)
      sumA[u] = wA + cvt4(W[u]);                    // A-frag(W + W^T)
      hvB[u] = ldBcol(chol_hv + off[u], g, l);      // B-frag(Hv) (= A-frag(Hv^T))
      M1[u] = MF(pinvA[u], hvB[u], zz);             // M1 = Pinv@Hv
      Up[u] = MF(sumA[u], hvB[u], zz);              // U' = (W+W^T)@Hv
    }
    #pragma unroll
    for (int u = 0; u < 2; ++u) {
      f16x4 hvtB = ldBcol(chol_hv_TE + off[u], g, l); // A-frag(HvT^T)
      Zt[u] = MF(hvtB, cvt4(M1[u]), zz);            // Z = HvT^T@M1
      V2[u] = MF(hvB[u], cvt4(Up[u]), zz);          // V2' = Hv^T@U'
      stCP(Q3[u], g, l, Zt[u]);
    }
    WBAR();
    f32x4 T1[2];
    #pragma unroll
    for (int u = 0; u < 2; ++u) {
      f16x4 zA = ldsA(Q3[u], l, g);                 // Z^T in D layout (f16)
      f32x4 am = V2[u] - Zt[u];                     // amatTE = V2' - Z - Z^T
      am[0] -= (float)zA[0]; am[1] -= (float)zA[1];
      am[2] -= (float)zA[2]; am[3] -= (float)zA[3];
      cA[u] = ldsB(Q2[u], g, l);                    // A-frag(cinv) (= B-frag(cinv^T))
      T1[u] = MF(cA[u], cvt4(am), zz);              // T1 = cinv@amatTE
      stCP(Q3[u], g, l, T1[u]);
    }
    WBAR();
    #pragma unroll
    for (int u = 0; u < 2; ++u) {
      f16x4 t1A = ldsA(Q3[u], l, g);
      f32x4 arg = MF(t1A, cA[u], zz);               // arg = T1@cinv^T
      #pragma unroll
      for (int j = 0; j < 4; ++j) {                 // phi mask
        const int r = 4 * g + j;
        arg[j] = (r > l) ? arg[j] : ((r == l) ? 0.5f * arg[j] : 0.f);
      }
      f32x4 cam = MF(ldA(chol_amat + off[u], l, g), cvt4(arg), zz);  // La@masked
      f16x4 laB = ldsB(Q1[u], g, l);                // B-frag(La)
      f32x4 ov = MF(ldA(chol_v_TE + off[u], l, g), laB, zz);         // LvT@La
      ov = MF(ldA(chol_v + off[u], l, g), cvt4(cam), ov);            // + Lv@cam
      float* ob = out + off[u];
      #pragma unroll
      for (int j = 0; j < 4; ++j) ob[(4 * g + j) * 16 + l] = ov[j];
    }
  }
}

extern "C" void kernel_launch(void* const* d_in, const int* in_sizes, int n_in,
                              void* d_out, int out_size, void* d_ws, size_t ws_size,
                              hipStream_t stream) {
  const float* mu_TE      = (const float*)d_in[0];
  const float* prec_h     = (const float*)d_in[1];
  const float* chol_v     = (const float*)d_in[2];
  const float* chol_h     = (const float*)d_in[3];
  const float* chol_hv    = (const float*)d_in[4];
  const float* chol_v_TE  = (const float*)d_in[5];
  const float* chol_h_TE  = (const float*)d_in[6];
  const float* chol_hv_TE = (const float*)d_in[7];
  const float* chol_amat  = (const float*)d_in[8];
  float* out = (float*)d_out;

  const int B = in_sizes[0] / 32;       // mu_TE is (B, 32)
  gauss_te_mf<<<B / 4, 64, 0, stream>>>(mu_TE, prec_h, chol_v, chol_h, chol_hv,
                                        chol_v_TE, chol_h_TE, chol_hv_TE,
                                        chol_amat, out, B);
}

// Round 9
// 121.970 us; speedup vs baseline: 5.9365x; 1.0378x over previous
//
#include <hip/hip_runtime.h>

// ConvertParamsTEtoParams0TEGaussLayer — MFMA v2: swizzle-GJ + symmetry chain.
// 64-thread blocks = 1 wave = 4 batches. GJ inverse of prec_h runs on DPP/
// ds_swizzle broadcasts (no LDS round-trips); all products on the matrix pipe
// (v_mfma_f32_16x16x16_f16). Transposes eliminated algebraically:
//   A-frag(X) == B-frag(X^T) (same registers);
//   S^T computed by swapping frag roles (no new loads);
//   symS = S+S^T symmetric  => A-frag(symS) = cvt4(symS);
//   Pinv symmetric          => one fragment serves A and B roles;
//   U' = (W+W^T)@Hv = Pinv@(symS@(Pinv@Hv)) — W/W1 never materialized;
//   Z^T = M1^T@HvT = MF(cvt4(M1), hvtB).
// Only cinv@amatTE@cinv^T needs one LDS round-trip (T1), reusing the dead
// Pinv image slot. LDS: 3 slots/batch = 488 u32 -> 7808 B/block -> 20 blk/CU.

typedef _Float16 h2    __attribute__((ext_vector_type(2)));
typedef _Float16 f16x4 __attribute__((ext_vector_type(4)));
typedef float    f32x4 __attribute__((ext_vector_type(4)));

constexpr int PITCH = 20;             // u32 per kp-row
constexpr int IMG   = 8 * PITCH;      // 160 u32 per packed image
constexpr int BSTR  = 3 * IMG + 8;    // 488 u32; %32==8 -> bank skew per batch

#define WBAR() __builtin_amdgcn_wave_barrier()

__device__ __forceinline__ unsigned int pkf(float a, float b) {
  return __builtin_bit_cast(unsigned int, __builtin_amdgcn_cvt_pkrtz(a, b));
}
__device__ __forceinline__ f16x4 mkf16x4(unsigned int lo, unsigned int hi) {
  union { unsigned int u[2]; f16x4 v; } cv; cv.u[0] = lo; cv.u[1] = hi; return cv.v;
}
__device__ __forceinline__ f16x4 cvt4(f32x4 d) {
  return mkf16x4(pkf(d[0], d[1]), pkf(d[2], d[3]));
}
__device__ __forceinline__ f16x4 cvt4f(float a, float b, float c, float d) {
  return mkf16x4(pkf(a, b), pkf(c, d));
}
__device__ __forceinline__ float dpp_swap1(float v) {  // lane c <-> c^1
  return __int_as_float(__builtin_amdgcn_update_dpp(
      0, __float_as_int(v), 0xB1, 0xF, 0xF, false));
}
__device__ __forceinline__ f32x4 MF(f16x4 a, f16x4 b, f32x4 c) {
  return __builtin_amdgcn_mfma_f32_16x16x16f16(a, b, c, 0, 0, 0);
}
__device__ __forceinline__ float frcp(float x) {
#if __has_builtin(__builtin_amdgcn_rcpf)
  return __builtin_amdgcn_rcpf(x);
#else
  return 1.0f / x;
#endif
}

// ---- tile-phase helpers (validated rounds 4-7) ----
__device__ __forceinline__ void ldtile(const float* __restrict__ g, size_t batch,
                                       int p, int q, float (&c)[16]) {
  const float* base = g + batch * 256 + p * 64 + q * 4;
  #pragma unroll
  for (int r = 0; r < 4; ++r) {
    float4 v = *reinterpret_cast<const float4*>(base + r * 16);
    c[r*4+0] = v.x; c[r*4+1] = v.y; c[r*4+2] = v.z; c[r*4+3] = v.w;
  }
}
__device__ __forceinline__ void storeRP(unsigned int* img, int p, int q, const float (&c)[16]) {
  #pragma unroll
  for (int r = 0; r < 4; ++r) {
    img[(2*q  ) * PITCH + 4*p + r] = pkf(c[r*4+0], c[r*4+1]);
    img[(2*q+1) * PITCH + 4*p + r] = pkf(c[r*4+2], c[r*4+3]);
  }
}
__device__ __forceinline__ void storeCPt(unsigned int* img, int p, int q, const float (&c)[16]) {
  uint4 w0, w1;
  w0.x = pkf(c[0],  c[4]);  w0.y = pkf(c[1],  c[5]);
  w0.z = pkf(c[2],  c[6]);  w0.w = pkf(c[3],  c[7]);
  w1.x = pkf(c[8],  c[12]); w1.y = pkf(c[9],  c[13]);
  w1.z = pkf(c[10], c[14]); w1.w = pkf(c[11], c[15]);
  *reinterpret_cast<uint4*>(img + (2*p  ) * PITCH + 4*q) = w0;
  *reinterpret_cast<uint4*>(img + (2*p+1) * PITCH + 4*q) = w1;
}

// ---- MFMA fragment helpers ----
// A-frag from global (row pattern): X[r][4h..4h+3]; also = B-frag(X^T).
__device__ __forceinline__ f16x4 ldA(const float* __restrict__ X, int r, int h) {
  float4 v = *reinterpret_cast<const float4*>(X + r * 16 + 4 * h);
  return cvt4f(v.x, v.y, v.z, v.w);
}
// B-frag from global (column pattern): X[4h+i][c]; also = A-frag(X^T).
__device__ __forceinline__ f16x4 ldBcol(const float* __restrict__ X, int h, int c) {
  const float* b = X + 4 * h * 16 + c;
  return cvt4f(b[0], b[16], b[32], b[48]);
}
// B-frag from CP image (or A-frag from RP image): 2x ds_read_b32.
__device__ __forceinline__ f16x4 ldsB(const unsigned int* img, int h, int c) {
  return mkf16x4(img[(2*h) * PITCH + c], img[(2*h+1) * PITCH + c]);
}
// A-frag from CP image (or B-frag from RP image): ds_read_b128 + 2x v_perm.
__device__ __forceinline__ f16x4 ldsA(const unsigned int* img, int r, int h) {
  uint4 u = *reinterpret_cast<const uint4*>(img + (r >> 1) * PITCH + 4 * h);
  unsigned int sel = 0x05040100u + (unsigned)(r & 1) * 0x02020202u;
  return mkf16x4(__builtin_amdgcn_perm(u.y, u.x, sel),
                 __builtin_amdgcn_perm(u.w, u.z, sel));
}
// D (f32x4) -> CP image: 2 pkrtz + 2 ds_write_b32.
__device__ __forceinline__ void stCP(unsigned int* img, int h, int c, f32x4 d) {
  img[(2*h)   * PITCH + c] = pkf(d[0], d[1]);
  img[(2*h+1) * PITCH + c] = pkf(d[2], d[3]);
}

__global__ __launch_bounds__(64, 4) void gauss_te_mf2(
    const float* __restrict__ mu_TE,
    const float* __restrict__ prec_h,
    const float* __restrict__ chol_v,
    const float* __restrict__ chol_h,
    const float* __restrict__ chol_hv,
    const float* __restrict__ chol_v_TE,
    const float* __restrict__ chol_h_TE,
    const float* __restrict__ chol_hv_TE,
    const float* __restrict__ chol_amat,
    float* __restrict__ out, int B)
{
  __shared__ __align__(16) unsigned int slab[4 * BSTR];
  const int t = threadIdx.x;
  const int g = t >> 4;                 // group / h-role
  const int l = t & 15;                 // lane-in-group / c-role
  const int p = l >> 2, q = l & 3;      // tile coords (GJ/subst phase)
  const size_t batch0 = (size_t)blockIdx.x * 4;
  const size_t tb = batch0 + g;

  unsigned int* Ut  = slab + g * BSTR;
  unsigned int* Q0t = Ut;               // RP(Pinv) -> T1 scratch
  unsigned int* Q1t = Ut + IMG;         // CP(La)
  unsigned int* Q2t = Ut + 2 * IMG;     // RP(cinv)

  // ---- muv_TE passthrough ----
  out[(size_t)B * 256 + tb * 16 + l] = mu_TE[tb * 32 + l];

  // ---- prefetch S-inputs for all 4 batches into f16 fragments ----
  f16x4 pfA0[4], pfB0[4], pfA1[4], pfB1[4];
  #pragma unroll
  for (int b = 0; b < 4; ++b) {
    const size_t off = (batch0 + b) * 256;
    pfA0[b] = ldA(chol_h_TE  + off, l, g);  // A-frag(LhT) = B-frag(LhT^T)
    pfB0[b] = ldA(chol_h     + off, l, g);  // B-frag(Lh^T) = A-frag(Lh)
    pfA1[b] = ldA(chol_hv_TE + off, l, g);  // A-frag(HvT) = B-frag(HvT^T)
    pfB1[b] = ldA(chol_hv    + off, l, g);  // B-frag(Hv^T) = A-frag(Hv)
  }
  float pt[16];
  ldtile(prec_h, tb, p, q, pt);

  // ---- Pinv = inv(prec_h): tile-layout GJ, DPP + ds_swizzle broadcasts ----
  // Per step K (kb=K>>2, kc=K&3, COMPILE-TIME via macro unroll):
  //   F[r] = P[4p+r][K] : quad_perm broadcast from lane (p,kb)
  //   br[j] = scaled pivot row chunk (rinv in the K-col slot), broadcast from
  //           lane (kb,q) via ds_swizzle BitMode and=0x13, or=kb<<2.
  #define GJ_STEP(K)                                                          \
  {                                                                           \
    constexpr int kb = (K) >> 2, kc = (K) & 3;                                \
    float F[4];                                                               \
    _Pragma("unroll")                                                         \
    for (int r = 0; r < 4; ++r)                                               \
      F[r] = __int_as_float(__builtin_amdgcn_update_dpp(                      \
          0, __float_as_int(pt[r*4+kc]), kb * 0x55, 0xF, 0xF, false));        \
    const float rinv = frcp(F[kc]);                                           \
    float sv[4];                                                              \
    _Pragma("unroll")                                                         \
    for (int j = 0; j < 4; ++j) sv[j] = pt[kc*4+j] * rinv;                    \
    if (q == kb) sv[kc] = rinv;                                               \
    float br[4];                                                              \
    _Pragma("unroll")                                                         \
    for (int j = 0; j < 4; ++j)                                               \
      br[j] = __int_as_float(__builtin_amdgcn_ds_swizzle(                     \
          __float_as_int(sv[j]), ((kb << 2) << 5) | 0x13));                   \
    _Pragma("unroll")                                                         \
    for (int r = 0; r < 4; ++r) {                                             \
      const bool isPivRow = (p == kb) && (r == kc);                           \
      _Pragma("unroll")                                                       \
      for (int j = 0; j < 4; ++j) {                                           \
        float base = pt[r*4+j];                                               \
        if (q == kb && j == kc) base = 0.f;                                   \
        const float nv = base - F[r] * br[j];                                 \
        pt[r*4+j] = isPivRow ? br[j] : nv;                                    \
      }                                                                       \
    }                                                                         \
  }
  GJ_STEP(0)  GJ_STEP(1)  GJ_STEP(2)  GJ_STEP(3)
  GJ_STEP(4)  GJ_STEP(5)  GJ_STEP(6)  GJ_STEP(7)
  GJ_STEP(8)  GJ_STEP(9)  GJ_STEP(10) GJ_STEP(11)
  GJ_STEP(12) GJ_STEP(13) GJ_STEP(14) GJ_STEP(15)
  #undef GJ_STEP
  storeRP(Q0t, p, q, pt);               // RP(Pinv) (== CP, symmetric)

  // ---- La: load tile, stage CP(La) ----
  float la[16];
  ldtile(chol_amat, tb, p, q, la);
  storeCPt(Q1t, p, q, la);
  WBAR();

  // ---- cinv: forward substitution (lane l = column l), reads CP(La) ----
  float x[16];
  #pragma unroll
  for (int kp = 0; kp < 8; ++kp) {
    const int r0 = 2 * kp, r1 = r0 + 1;
    float a0 = 0.f, a1 = 0.f, h10 = 0.f;
    #pragma unroll
    for (int c2 = 0; c2 <= kp / 2; ++c2) {
      uint4 cv = *reinterpret_cast<const uint4*>(Q1t + kp * PITCH + 4 * c2);
      const unsigned int cw[4] = {cv.x, cv.y, cv.z, cv.w};
      #pragma unroll
      for (int cc = 0; cc < 4; ++cc) {
        const int j = 4 * c2 + cc;
        h2 hp = __builtin_bit_cast(h2, cw[cc]);
        if (j < r0) a0 = fmaf(-(float)hp.x, x[j], a0);
        if (j < r0) a1 = fmaf(-(float)hp.y, x[j], a1);
        if (j == r0) h10 = (float)hp.y;
      }
    }
    x[r0] = ((l == r0) ? 1.f : 0.f) + a0;
    x[r1] = ((l == r1) ? 1.f : 0.f) + a1 - h10 * x[r0];
  }
  {
    float xp[16];
    #pragma unroll
    for (int j = 0; j < 16; ++j) xp[j] = dpp_swap1(x[j]);
    if ((l & 1) == 0) {                 // RP(cinv) -> Q2
      unsigned int* dst = Q2t + (l >> 1) * PITCH;
      #pragma unroll
      for (int c4 = 0; c4 < 4; ++c4) {
        uint4 w;
        w.x = pkf(x[4*c4+0], xp[4*c4+0]); w.y = pkf(x[4*c4+1], xp[4*c4+1]);
        w.z = pkf(x[4*c4+2], xp[4*c4+2]); w.w = pkf(x[4*c4+3], xp[4*c4+3]);
        *reinterpret_cast<uint4*>(dst + 4*c4) = w;
      }
    }
  }
  WBAR();

  // ---- MFMA phase: 2 batch-chains interleaved per pair ----
  const f32x4 zz = {0.f, 0.f, 0.f, 0.f};
  #pragma unroll
  for (int gb = 0; gb < 4; gb += 2) {
    const unsigned int* Q1[2] = { slab + (gb+0)*BSTR + IMG,
                                  slab + (gb+1)*BSTR + IMG };
    const unsigned int* Q2[2] = { slab + (gb+0)*BSTR + 2*IMG,
                                  slab + (gb+1)*BSTR + 2*IMG };
    unsigned int*       Q0[2] = { slab + (gb+0)*BSTR, slab + (gb+1)*BSTR };
    const size_t off[2] = { (batch0 + gb + 0) * 256, (batch0 + gb + 1) * 256 };

    f16x4 pinvF[2], hvB[2], hvtB[2], cA[2];
    #pragma unroll
    for (int u = 0; u < 2; ++u) {
      hvB[u]  = ldBcol(chol_hv + off[u], g, l);     // B-frag(Hv) = A-frag(Hv^T)
      hvtB[u] = ldBcol(chol_hv_TE + off[u], g, l);  // B-frag(HvT) = A-frag(HvT^T)
      pinvF[u] = ldsA(Q0[u], l, g);                 // Pinv frag (A==B, symmetric)
      cA[u] = ldsB(Q2[u], g, l);                    // A-frag(cinv) = B-frag(cinv^T)
    }
    #pragma unroll
    for (int u = 0; u < 2; ++u) {
      f32x4 S  = MF(pfA0[gb+u], pfB0[gb+u], zz);    // LhT @ Lh^T
      S        = MF(pfA1[gb+u], pfB1[gb+u], S);     // + HvT @ Hv^T
      f32x4 St = MF(pfB0[gb+u], pfA0[gb+u], zz);    // Lh @ LhT^T   (= S^T)
      St       = MF(pfB1[gb+u], pfA1[gb+u], St);    // + Hv @ HvT^T
      f32x4 sy = S + St;                            // symS (symmetric)
      f32x4 M1 = MF(pinvF[u], hvB[u], zz);          // M1 = Pinv@Hv
      f16x4 m1h = cvt4(M1);
      f32x4 G  = MF(cvt4(sy), m1h, zz);             // G = symS@M1 (symS as A)
      f32x4 Up = MF(pinvF[u], cvt4(G), zz);         // U' = Pinv@G = (W+W^T)@Hv
      f32x4 Z  = MF(hvtB[u], m1h, zz);              // Z   = HvT^T@M1
      f32x4 ZT = MF(m1h, hvtB[u], zz);              // Z^T = M1^T@HvT
      f32x4 V2 = MF(hvB[u], cvt4(Up), zz);          // V2' = Hv^T@U'
      f32x4 am = V2 - Z - ZT;                       // amatTE
      f32x4 T1 = MF(cA[u], cvt4(am), zz);           // T1 = cinv@amatTE
      stCP(Q0[u], g, l, T1);                        // scratch (Pinv dead)
    }
    WBAR();
    #pragma unroll
    for (int u = 0; u < 2; ++u) {
      f16x4 t1A = ldsA(Q0[u], l, g);
      f32x4 arg = MF(t1A, cA[u], zz);               // arg = T1@cinv^T
      #pragma unroll
      for (int j = 0; j < 4; ++j) {                 // phi mask
        const int r = 4 * g + j;
        arg[j] = (r > l) ? arg[j] : ((r == l) ? 0.5f * arg[j] : 0.f);
      }
      f32x4 cam = MF(ldA(chol_amat + off[u], l, g), cvt4(arg), zz);  // La@masked
      f32x4 ov = MF(ldA(chol_v_TE + off[u], l, g), ldsB(Q1[u], g, l), zz); // LvT@La
      ov = MF(ldA(chol_v + off[u], l, g), cvt4(cam), ov);            // + Lv@cam
      float* ob = out + off[u];
      #pragma unroll
      for (int j = 0; j < 4; ++j) ob[(4 * g + j) * 16 + l] = ov[j];
    }
  }
}

extern "C" void kernel_launch(void* const* d_in, const int* in_sizes, int n_in,
                              void* d_out, int out_size, void* d_ws, size_t ws_size,
                              hipStream_t stream) {
  const float* mu_TE      = (const float*)d_in[0];
  const float* prec_h     = (const float*)d_in[1];
  const float* chol_v     = (const float*)d_in[2];
  const float* chol_h     = (const float*)d_in[3];
  const float* chol_hv    = (const float*)d_in[4];
  const float* chol_v_TE  = (const float*)d_in[5];
  const float* chol_h_TE  = (const float*)d_in[6];
  const float* chol_hv_TE = (const float*)d_in[7];
  const float* chol_amat  = (const float*)d_in[8];
  float* out = (float*)d_out;

  const int B = in_sizes[0] / 32;       // mu_TE is (B, 32)
  gauss_te_mf2<<<B / 4, 64, 0, stream>>>(mu_TE, prec_h, chol_v, chol_h, chol_hv,
                                         chol_v_TE, chol_h_TE, chol_hv_TE,
                                         chol_amat, out, B);
}